// Round 2
// baseline (1047.533 us; speedup 1.0000x reference)
//
#include <hip/hip_runtime.h>
#include <hip/hip_bf16.h>

#define N_NODES 131072
#define N_EDGES 2097152
#define BATCHES 256
#define LPATH   32

typedef __hip_bfloat16 bf16;
using short8  = __attribute__((ext_vector_type(8))) short;
using floatx4 = __attribute__((ext_vector_type(4))) float;

__device__ __forceinline__ float bl(unsigned u){ union {unsigned x; float f;} c; c.x = u << 16; return c.f; }
__device__ __forceinline__ float bh(unsigned u){ union {unsigned x; float f;} c; c.x = u & 0xffff0000u; return c.f; }
__device__ __forceinline__ unsigned packbf(float lo, float hi){
  bf16 l = __float2bfloat16(lo), h = __float2bfloat16(hi);
  unsigned short lu, hu;
  __builtin_memcpy(&lu, &l, 2); __builtin_memcpy(&hu, &h, 2);
  return (unsigned)lu | ((unsigned)hu << 16);
}
__device__ __forceinline__ float sigf(float x){ return 1.f / (1.f + __expf(-x)); }

// ---------------- prep: f32 weights -> bf16 (concat along K for SAGE layers) ----------------
// ranges: [0,16384) Wcat1 | [16384,49152) Wcat2 | [49152,114688) WihB | [114688,180224) WhhB | [180224,180736) bsumF
__global__ void prep_k(const float* __restrict__ Wl1, const float* __restrict__ Wr1,
                       const float* __restrict__ Wl2, const float* __restrict__ Wr2,
                       const float* __restrict__ Wih, const float* __restrict__ Whh,
                       const float* __restrict__ bih, const float* __restrict__ bhh,
                       bf16* __restrict__ Wcat1, bf16* __restrict__ Wcat2,
                       bf16* __restrict__ WihB, bf16* __restrict__ WhhB, float* __restrict__ bsumF){
  int g = blockIdx.x * 256 + threadIdx.x;
  if (g < 16384) {                    // Wcat1: 128 x 128 (Wl1 | Wr1), K split at 64
    int h = g >> 7, k = g & 127;
    float v = (k < 64) ? Wl1[h * 64 + k] : Wr1[h * 64 + (k - 64)];
    Wcat1[g] = __float2bfloat16(v);
  } else if (g < 49152) {             // Wcat2: 128 x 256 (Wl2 | Wr2), K split at 128
    int q = g - 16384;
    int h = q >> 8, k = q & 255;
    float v = (k < 128) ? Wl2[h * 128 + k] : Wr2[h * 128 + (k - 128)];
    Wcat2[q] = __float2bfloat16(v);
  } else if (g < 114688) {            // WihB: 512 x 128
    int q = g - 49152;
    WihB[q] = __float2bfloat16(Wih[q]);
  } else if (g < 180224) {            // WhhB: 512 x 128
    int q = g - 114688;
    WhhB[q] = __float2bfloat16(Whh[q]);
  } else if (g < 180736) {            // bsumF = bih + bhh (f32)
    int k = g - 180224;
    bsumF[k] = bih[k] + bhh[k];
  }
}

// ---------------- graph segment bounds (batch is sorted) ----------------
__global__ void bounds_k(const int* __restrict__ batch, int* __restrict__ starts){
  int b = threadIdx.x;
  int lo = 0, hi = N_NODES;
  while (lo < hi){ int mid = (lo + hi) >> 1; if (batch[mid] < b) lo = mid + 1; else hi = mid; }
  starts[b] = lo;
  if (b == 0) starts[BATCHES] = N_NODES;
}

// ---------------- CSR build ----------------
__global__ void hist_k(const int* __restrict__ dst, int* __restrict__ cnt){
  int e = blockIdx.x * 256 + threadIdx.x;
  atomicAdd(&cnt[dst[e]], 1);
}

__global__ void scan1_k(const int* __restrict__ cnt, int* __restrict__ offs, int* __restrict__ bsum){
  __shared__ int sh[256];
  int t = threadIdx.x, i = blockIdx.x * 256 + t;
  int v = cnt[i];
  sh[t] = v; __syncthreads();
  int inc = v;
  for (int d = 1; d < 256; d <<= 1){
    int add = (t >= d) ? sh[t - d] : 0;
    __syncthreads();
    inc += add; sh[t] = inc;
    __syncthreads();
  }
  offs[i] = inc - v;
  if (t == 255) bsum[blockIdx.x] = inc;
}

__global__ void scan2_k(const int* __restrict__ bsum, int* __restrict__ bsumEx){
  __shared__ int sh[512];
  int t = threadIdx.x;
  int v = bsum[t];
  sh[t] = v; __syncthreads();
  int inc = v;
  for (int d = 1; d < 512; d <<= 1){
    int add = (t >= d) ? sh[t - d] : 0;
    __syncthreads();
    inc += add; sh[t] = inc;
    __syncthreads();
  }
  bsumEx[t] = inc - v;
}

__global__ void scan3_k(int* __restrict__ offs, const int* __restrict__ bsumEx, int* __restrict__ cursor){
  int i = blockIdx.x * 256 + threadIdx.x;
  int v = offs[i] + bsumEx[i >> 8];
  offs[i] = v; cursor[i] = v;
  if (i == 0) offs[N_NODES] = N_EDGES;
}

__global__ void scatter_k(const int* __restrict__ src, const int* __restrict__ dst,
                          int* __restrict__ cursor, int* __restrict__ srcS){
  int e = blockIdx.x * 256 + threadIdx.x;
  int d = dst[e];
  int p = atomicAdd(&cursor[d], 1);
  srcS[p] = src[e];
}

// ---------------- SAGE layer-1 aggregation: mean of x[src] + copy x (f32 -> bf16) ----------------
__global__ void agg1_k(const float* __restrict__ x, const int* __restrict__ offs,
                       const int* __restrict__ srcS, bf16* __restrict__ Acat1){
  int wid = threadIdx.x >> 6, lane = threadIdx.x & 63;
  int n = blockIdx.x * 4 + wid;
  int s = offs[n], e = offs[n + 1];
  float acc = 0.f;
  for (int i = s; i < e; ++i){
    int sv = srcS[i];
    acc += x[(size_t)sv * 64 + lane];
  }
  int d = e - s; if (d < 1) d = 1;
  Acat1[(size_t)n * 128 + lane]      = __float2bfloat16(acc / (float)d);
  Acat1[(size_t)n * 128 + 64 + lane] = __float2bfloat16(x[(size_t)n * 64 + lane]);
}

// ---------------- SAGE layer-2 aggregation: mean of h1[src] (h1 in Acat2[:,128:256], bf16) ----------------
__global__ void agg2_k(const int* __restrict__ offs, const int* __restrict__ srcS, bf16* __restrict__ Acat2){
  int wid = threadIdx.x >> 6, lane = threadIdx.x & 63;
  int n = blockIdx.x * 4 + wid;
  int s = offs[n], e = offs[n + 1];
  float a0 = 0.f, a1 = 0.f;
  for (int i = s; i < e; ++i){
    int sv = srcS[i];
    unsigned u = *(const unsigned*)(Acat2 + (size_t)sv * 256 + 128 + lane * 2);
    a0 += bl(u); a1 += bh(u);
  }
  int d = e - s; if (d < 1) d = 1;
  float inv = 1.f / (float)d;
  *(unsigned*)(Acat2 + (size_t)n * 256 + lane * 2) = packbf(a0 * inv, a1 * inv);
}

// ---------------- generic MFMA GEMM: out[M x Ncols] = act(A[M x K] @ W[Ncols x K]^T + bias) ----------------
// block = 256 thr (4 waves); covers 64 rows x 128 cols (colGroup = blockIdx.y*128)
__global__ __launch_bounds__(256) void gemm_k(const bf16* __restrict__ A, int lda,
                                              const bf16* __restrict__ W, int K,
                                              const float* __restrict__ bias,
                                              void* __restrict__ out, int ldo, int outF32, int relu){
  __shared__ bf16 Wl[128][136];   // +8 pad: 2-way bank aliasing only
  int tid = threadIdx.x;
  int wid = tid >> 6, lane = tid & 63;
  int l16 = lane & 15, quad = lane >> 4;
  int rowBase  = blockIdx.x * 64 + wid * 16;
  int colGroup = blockIdx.y * 128;
  floatx4 acc[8] = {};
  int nStage = K >> 7;
  for (int ks = 0; ks < nStage; ++ks){
    __syncthreads();
    for (int c = tid; c < 2048; c += 256){
      int r = c >> 4, kc = (c & 15) << 3;
      *(uint4*)(&Wl[r][kc]) = *(const uint4*)(W + (size_t)(colGroup + r) * K + ks * 128 + kc);
    }
    __syncthreads();
    for (int kk = 0; kk < 4; ++kk){
      short8 af = *(const short8*)(A + (size_t)(rowBase + l16) * lda + ks * 128 + kk * 32 + quad * 8);
      #pragma unroll
      for (int c = 0; c < 8; ++c){
        short8 bq = *(const short8*)(&Wl[c * 16 + l16][kk * 32 + quad * 8]);
        acc[c] = __builtin_amdgcn_mfma_f32_16x16x32_bf16(af, bq, acc[c], 0, 0, 0);
      }
    }
  }
  #pragma unroll
  for (int c = 0; c < 8; ++c){
    int col = colGroup + c * 16 + l16;
    float bv = bias ? bias[col] : 0.f;
    #pragma unroll
    for (int r = 0; r < 4; ++r){
      int row = rowBase + quad * 4 + r;
      float v = acc[c][r] + bv;
      if (relu) v = fmaxf(v, 0.f);
      if (outF32) ((float*)out)[(size_t)row * ldo + col] = v;
      else        ((bf16*)out)[(size_t)row * ldo + col]  = __float2bfloat16(v);
    }
  }
}

// ---------------- graph mean pooling (sorted batch, segment bounds) ----------------
__global__ void pool_k(const bf16* __restrict__ ne, const int* __restrict__ starts, float* __restrict__ comb){
  int b = blockIdx.x, f = threadIdx.x;   // 128 threads
  int s = starts[b], e = starts[b + 1];
  float acc = 0.f;
  for (int i = s; i < e; ++i) acc += __bfloat162float(ne[(size_t)i * 128 + f]);
  int d = e - s; if (d < 1) d = 1;
  comb[b * 320 + f] = acc / (float)d;
}

// ---------------- flow MLP: relu(flow @ Wf^T + bf), all f32 ----------------
__global__ void flow_k(const float* __restrict__ flow, const float* __restrict__ Wf,
                       const float* __restrict__ bfv, float* __restrict__ comb){
  int g = blockIdx.x * 256 + threadIdx.x;
  int b = g >> 6, j = g & 63;
  float acc = bfv[j];
  for (int k = 0; k < 16; ++k)
    acc += flow[b * 16 + k] * Wf[j * 16 + k];
  comb[b * 320 + 256 + j] = fmaxf(acc, 0.f);
}

// ---------------- gather path sequences (bf16 node_emb rows) ----------------
__global__ void gather_k(const int* __restrict__ path_idx, const bf16* __restrict__ ne, bf16* __restrict__ ps){
  int wid = threadIdx.x >> 6, lane = threadIdx.x & 63;
  int r = blockIdx.x * 4 + wid;          // r in [0, B*L)
  int idx = path_idx[r];
  ((unsigned*)ps)[(size_t)r * 64 + lane] = ((const unsigned*)ne)[(size_t)idx * 64 + lane];
}

// ---------------- LSTM recurrence: one block per batch, WhhB (bf16) in VGPRs ----------------
__global__ __launch_bounds__(256, 1) void lstm_k(const bf16* __restrict__ Whh, const float* __restrict__ pre,
                                                 const int* __restrict__ path_len, float* __restrict__ comb){
  __shared__ float h[128];
  __shared__ float g[512];
  int b = blockIdx.x, j = threadIdx.x;
  uint4 wa[16], wb[16];
  const uint4* w0 = (const uint4*)(Whh + (size_t)j * 128);
  const uint4* w1 = (const uint4*)(Whh + (size_t)(j + 256) * 128);
  #pragma unroll
  for (int k = 0; k < 16; ++k){ wa[k] = w0[k]; wb[k] = w1[k]; }
  if (j < 128) h[j] = 0.f;
  float c = 0.f, hn = 0.f;
  int len = path_len[b]; if (len < 1) len = 1; if (len > LPATH) len = LPATH;
  const float4* hv4 = (const float4*)h;
  for (int t = 0; t < len; ++t){
    __syncthreads();                                   // h ready
    float a0 = pre[((size_t)b * LPATH + t) * 512 + j];
    float a1 = pre[((size_t)b * LPATH + t) * 512 + j + 256];
    #pragma unroll
    for (int k = 0; k < 16; ++k){
      float4 h0 = hv4[2 * k], h1 = hv4[2 * k + 1];
      uint4 u = wa[k], v = wb[k];
      a0 = fmaf(bl(u.x), h0.x, a0); a0 = fmaf(bh(u.x), h0.y, a0);
      a0 = fmaf(bl(u.y), h0.z, a0); a0 = fmaf(bh(u.y), h0.w, a0);
      a0 = fmaf(bl(u.z), h1.x, a0); a0 = fmaf(bh(u.z), h1.y, a0);
      a0 = fmaf(bl(u.w), h1.z, a0); a0 = fmaf(bh(u.w), h1.w, a0);
      a1 = fmaf(bl(v.x), h0.x, a1); a1 = fmaf(bh(v.x), h0.y, a1);
      a1 = fmaf(bl(v.y), h0.z, a1); a1 = fmaf(bh(v.y), h0.w, a1);
      a1 = fmaf(bl(v.z), h1.x, a1); a1 = fmaf(bh(v.z), h1.y, a1);
      a1 = fmaf(bl(v.w), h1.z, a1); a1 = fmaf(bh(v.w), h1.w, a1);
    }
    g[j] = a0; g[j + 256] = a1;
    __syncthreads();                                   // gates ready
    if (j < 128){
      float ig = sigf(g[j]), fg = sigf(g[j + 128]);
      float gg = tanhf(g[j + 256]), og = sigf(g[j + 384]);
      c = fg * c + ig * gg;
      hn = og * tanhf(c);
      h[j] = hn;
    }
  }
  if (j < 128) comb[b * 320 + 128 + j] = hn;
}

// ---------------- scoring head (f32 weights) ----------------
__global__ void head_k(const float* __restrict__ comb, const float* __restrict__ Ws1, const float* __restrict__ bs1,
                       const float* __restrict__ Ws2, const float* __restrict__ bs2, float* __restrict__ out){
  __shared__ float cl[320];
  __shared__ float red[128];
  int b = blockIdx.x, j = threadIdx.x;   // 128 threads
  for (int k = j; k < 320; k += 128) cl[k] = comb[b * 320 + k];
  __syncthreads();
  float acc = bs1[j];
  const float4* wr = (const float4*)(Ws1 + (size_t)j * 320);
  #pragma unroll 4
  for (int kc = 0; kc < 80; ++kc){
    float4 u = wr[kc];
    int k = kc * 4;
    acc += u.x * cl[k] + u.y * cl[k + 1] + u.z * cl[k + 2] + u.w * cl[k + 3];
  }
  float hv = fmaxf(acc, 0.f);
  red[j] = hv * Ws2[j];
  __syncthreads();
  for (int s = 64; s > 0; s >>= 1){ if (j < s) red[j] += red[j + s]; __syncthreads(); }
  if (j == 0) out[b] = red[0] + bs2[0];
}

// ---------------- workspace layout (all offsets 16B-aligned) ----------------
constexpr size_t OFF_CNT    = 0;
constexpr size_t OFF_OFFS   = OFF_CNT    + 524288;     // N ints
constexpr size_t OFF_CURSOR = OFF_OFFS   + 525312;     // (N+1) ints, padded
constexpr size_t OFF_BSUM   = OFF_CURSOR + 524288;
constexpr size_t OFF_BSUMEX = OFF_BSUM   + 2048;
constexpr size_t OFF_STARTS = OFF_BSUMEX + 2048;
constexpr size_t OFF_SRCS   = OFF_STARTS + 2048;
constexpr size_t OFF_WCAT1  = OFF_SRCS   + 8388608;    // E ints
constexpr size_t OFF_WCAT2  = OFF_WCAT1  + 32768;      // 128x128 bf16
constexpr size_t OFF_WIHB   = OFF_WCAT2  + 65536;      // 128x256 bf16
constexpr size_t OFF_WHHB   = OFF_WIHB   + 131072;     // 512x128 bf16
constexpr size_t OFF_BSUMF  = OFF_WHHB   + 131072;     // 512x128 bf16
constexpr size_t OFF_COMB   = OFF_BSUMF  + 2048;       // 512 f32
constexpr size_t OFF_ACAT1  = OFF_COMB   + 327680;     // N x 128 bf16; node_emb aliases after GEMM1
constexpr size_t OFF_ACAT2  = OFF_ACAT1  + 33554432;   // N x 256 bf16; pathseq+pre alias after GEMM2
constexpr size_t OFF_PATHSEQ= OFF_ACAT2;               // 8192 x 128 bf16 (2 MB)
constexpr size_t OFF_PRE    = OFF_ACAT2  + 2097152;    // 8192 x 512 f32 (16.8 MB)

extern "C" void kernel_launch(void* const* d_in, const int* in_sizes, int n_in,
                              void* d_out, int out_size, void* d_ws, size_t ws_size,
                              hipStream_t stream){
  const float* x      = (const float*)d_in[0];
  const int* edge     = (const int*)d_in[1];
  const int* batch    = (const int*)d_in[2];
  const int* path_idx = (const int*)d_in[3];
  const int* path_len = (const int*)d_in[4];
  const float* flow   = (const float*)d_in[5];
  const float* Wl1 = (const float*)d_in[6];
  const float* Wr1 = (const float*)d_in[7];
  const float* b1  = (const float*)d_in[8];
  const float* Wl2 = (const float*)d_in[9];
  const float* Wr2 = (const float*)d_in[10];
  const float* b2  = (const float*)d_in[11];
  const float* Wih = (const float*)d_in[12];
  const float* Whh = (const float*)d_in[13];
  const float* bih = (const float*)d_in[14];
  const float* bhh = (const float*)d_in[15];
  const float* Wf  = (const float*)d_in[16];
  const float* bfv = (const float*)d_in[17];
  const float* Ws1 = (const float*)d_in[18];
  const float* bs1 = (const float*)d_in[19];
  const float* Ws2 = (const float*)d_in[20];
  const float* bs2 = (const float*)d_in[21];

  char* ws = (char*)d_ws;
  int* cnt     = (int*)(ws + OFF_CNT);
  int* offs    = (int*)(ws + OFF_OFFS);
  int* cursor  = (int*)(ws + OFF_CURSOR);
  int* bsum    = (int*)(ws + OFF_BSUM);
  int* bsumEx  = (int*)(ws + OFF_BSUMEX);
  int* starts  = (int*)(ws + OFF_STARTS);
  int* srcS    = (int*)(ws + OFF_SRCS);
  bf16* Wcat1  = (bf16*)(ws + OFF_WCAT1);
  bf16* Wcat2  = (bf16*)(ws + OFF_WCAT2);
  bf16* WihB   = (bf16*)(ws + OFF_WIHB);
  bf16* WhhB   = (bf16*)(ws + OFF_WHHB);
  float* bsumF = (float*)(ws + OFF_BSUMF);
  float* comb  = (float*)(ws + OFF_COMB);
  bf16* Acat1  = (bf16*)(ws + OFF_ACAT1);
  bf16* node_emb = Acat1;                       // alias: Acat1 dead after GEMM1
  bf16* Acat2  = (bf16*)(ws + OFF_ACAT2);
  bf16* pathseq= (bf16*)(ws + OFF_PATHSEQ);     // alias: Acat2 dead after GEMM2
  float* pre   = (float*)(ws + OFF_PRE);

  hipMemsetAsync(cnt, 0, N_NODES * sizeof(int), stream);
  prep_k<<<707, 256, 0, stream>>>(Wl1, Wr1, Wl2, Wr2, Wih, Whh, bih, bhh, Wcat1, Wcat2, WihB, WhhB, bsumF);
  bounds_k<<<1, 256, 0, stream>>>(batch, starts);
  hist_k<<<N_EDGES / 256, 256, 0, stream>>>(edge + N_EDGES, cnt);
  scan1_k<<<N_NODES / 256, 256, 0, stream>>>(cnt, offs, bsum);
  scan2_k<<<1, 512, 0, stream>>>(bsum, bsumEx);
  scan3_k<<<N_NODES / 256, 256, 0, stream>>>(offs, bsumEx, cursor);
  scatter_k<<<N_EDGES / 256, 256, 0, stream>>>(edge, edge + N_EDGES, cursor, srcS);
  agg1_k<<<N_NODES / 4, 256, 0, stream>>>(x, offs, srcS, Acat1);
  gemm_k<<<dim3(N_NODES / 64, 1), 256, 0, stream>>>(Acat1, 128, Wcat1, 128, b1, Acat2 + 128, 256, 0, 1);
  agg2_k<<<N_NODES / 4, 256, 0, stream>>>(offs, srcS, Acat2);
  gemm_k<<<dim3(N_NODES / 64, 1), 256, 0, stream>>>(Acat2, 256, Wcat2, 256, b2, node_emb, 128, 0, 1);
  pool_k<<<BATCHES, 128, 0, stream>>>(node_emb, starts, comb);
  flow_k<<<64, 256, 0, stream>>>(flow, Wf, bfv, comb);
  gather_k<<<BATCHES * LPATH / 4, 256, 0, stream>>>(path_idx, node_emb, pathseq);
  gemm_k<<<dim3(BATCHES * LPATH / 64, 4), 256, 0, stream>>>(pathseq, 128, WihB, 128, bsumF, pre, 512, 1, 0);
  lstm_k<<<BATCHES, 256, 0, stream>>>(WhhB, pre, path_len, comb);
  head_k<<<BATCHES, 128, 0, stream>>>(comb, Ws1, bs1, Ws2, bs2, (float*)d_out);
}

// Round 3
// 702.787 us; speedup vs baseline: 1.4905x; 1.4905x over previous
//
#include <hip/hip_runtime.h>
#include <hip/hip_bf16.h>

#define N_NODES 131072
#define N_EDGES 2097152
#define BATCHES 256
#define LPATH   32

typedef __hip_bfloat16 bf16;
using short8  = __attribute__((ext_vector_type(8))) short;
using floatx4 = __attribute__((ext_vector_type(4))) float;

__device__ __forceinline__ float bl(unsigned u){ union {unsigned x; float f;} c; c.x = u << 16; return c.f; }
__device__ __forceinline__ float bh(unsigned u){ union {unsigned x; float f;} c; c.x = u & 0xffff0000u; return c.f; }
__device__ __forceinline__ unsigned packbf(float lo, float hi){
  bf16 l = __float2bfloat16(lo), h = __float2bfloat16(hi);
  unsigned short lu, hu;
  __builtin_memcpy(&lu, &l, 2); __builtin_memcpy(&hu, &h, 2);
  return (unsigned)lu | ((unsigned)hu << 16);
}
__device__ __forceinline__ float sigf(float x){ return 1.f / (1.f + __expf(-x)); }

// ---------------- prep: f32 weights -> bf16 (concat along K for SAGE layers) ----------------
__global__ void prep_k(const float* __restrict__ Wl1, const float* __restrict__ Wr1,
                       const float* __restrict__ Wl2, const float* __restrict__ Wr2,
                       const float* __restrict__ Wih, const float* __restrict__ Whh,
                       const float* __restrict__ bih, const float* __restrict__ bhh,
                       bf16* __restrict__ Wcat1, bf16* __restrict__ Wcat2,
                       bf16* __restrict__ WihB, bf16* __restrict__ WhhB, float* __restrict__ bsumF){
  int g = blockIdx.x * 256 + threadIdx.x;
  if (g < 16384) {                    // Wcat1: 128 x 128 (Wl1 | Wr1), K split at 64
    int h = g >> 7, k = g & 127;
    float v = (k < 64) ? Wl1[h * 64 + k] : Wr1[h * 64 + (k - 64)];
    Wcat1[g] = __float2bfloat16(v);
  } else if (g < 49152) {             // Wcat2: 128 x 256 (Wl2 | Wr2), K split at 128
    int q = g - 16384;
    int h = q >> 8, k = q & 255;
    float v = (k < 128) ? Wl2[h * 128 + k] : Wr2[h * 128 + (k - 128)];
    Wcat2[q] = __float2bfloat16(v);
  } else if (g < 114688) {            // WihB: 512 x 128
    int q = g - 49152;
    WihB[q] = __float2bfloat16(Wih[q]);
  } else if (g < 180224) {            // WhhB: 512 x 128
    int q = g - 114688;
    WhhB[q] = __float2bfloat16(Whh[q]);
  } else if (g < 180736) {            // bsumF = bih + bhh (f32)
    int k = g - 180224;
    bsumF[k] = bih[k] + bhh[k];
  }
}

// ---------------- x (f32) -> xb (bf16) + self-half of Acat1 ----------------
__global__ void xb16_k(const float* __restrict__ x, bf16* __restrict__ xb, bf16* __restrict__ Acat1){
  int g = blockIdx.x * 256 + threadIdx.x;     // one thread per 2 features
  int n = g >> 5, p = g & 31;
  float2 v = *(const float2*)(x + (size_t)n * 64 + p * 2);
  unsigned u = packbf(v.x, v.y);
  *(unsigned*)(xb + (size_t)n * 64 + p * 2) = u;
  *(unsigned*)(Acat1 + (size_t)n * 128 + 64 + p * 2) = u;
}

// ---------------- graph segment bounds (batch is sorted) ----------------
__global__ void bounds_k(const int* __restrict__ batch, int* __restrict__ starts){
  int b = threadIdx.x;
  int lo = 0, hi = N_NODES;
  while (lo < hi){ int mid = (lo + hi) >> 1; if (batch[mid] < b) lo = mid + 1; else hi = mid; }
  starts[b] = lo;
  if (b == 0) starts[BATCHES] = N_NODES;
}

// ---------------- CSR build ----------------
__global__ void hist_k(const int* __restrict__ dst, int* __restrict__ cnt){
  int e = blockIdx.x * 256 + threadIdx.x;
  atomicAdd(&cnt[dst[e]], 1);
}

__global__ void scan1_k(const int* __restrict__ cnt, int* __restrict__ offs, int* __restrict__ bsum){
  __shared__ int sh[256];
  int t = threadIdx.x, i = blockIdx.x * 256 + t;
  int v = cnt[i];
  sh[t] = v; __syncthreads();
  int inc = v;
  for (int d = 1; d < 256; d <<= 1){
    int add = (t >= d) ? sh[t - d] : 0;
    __syncthreads();
    inc += add; sh[t] = inc;
    __syncthreads();
  }
  offs[i] = inc - v;
  if (t == 255) bsum[blockIdx.x] = inc;
}

__global__ void scan2_k(const int* __restrict__ bsum, int* __restrict__ bsumEx){
  __shared__ int sh[512];
  int t = threadIdx.x;
  int v = bsum[t];
  sh[t] = v; __syncthreads();
  int inc = v;
  for (int d = 1; d < 512; d <<= 1){
    int add = (t >= d) ? sh[t - d] : 0;
    __syncthreads();
    inc += add; sh[t] = inc;
    __syncthreads();
  }
  bsumEx[t] = inc - v;
}

__global__ void scan3_k(int* __restrict__ offs, const int* __restrict__ bsumEx, int* __restrict__ cursor){
  int i = blockIdx.x * 256 + threadIdx.x;
  int v = offs[i] + bsumEx[i >> 8];
  offs[i] = v; cursor[i] = v;
  if (i == 0) offs[N_NODES] = N_EDGES;
}

__global__ void scatter_k(const int* __restrict__ src, const int* __restrict__ dst,
                          int* __restrict__ cursor, int* __restrict__ srcS){
  int e = blockIdx.x * 256 + threadIdx.x;
  int d = dst[e];
  int p = atomicAdd(&cursor[d], 1);
  srcS[p] = src[e];
}

// ---------------- SAGE layer-1 aggregation: mean of xb[src] over 4 edge-slots ----------------
// wave = 4 edge-slots x 16 lanes; each lane loads uint2 (4 bf16); unroll 2 -> 8 loads in flight
__global__ void agg1_k(const bf16* __restrict__ xb, const int* __restrict__ offs,
                       const int* __restrict__ srcS, bf16* __restrict__ Acat1){
  int wid = threadIdx.x >> 6, lane = threadIdx.x & 63;
  int n = blockIdx.x * 4 + wid;
  int s = offs[n], e = offs[n + 1];
  int slot = lane >> 4, fl = lane & 15;
  float a0 = 0.f, a1 = 0.f, a2 = 0.f, a3 = 0.f;
  float c0 = 0.f, c1 = 0.f, c2 = 0.f, c3 = 0.f;
  int i = s + slot;
  for (; i + 4 < e; i += 8){
    int sv0 = srcS[i], sv1 = srcS[i + 4];
    uint2 u = *(const uint2*)(xb + (size_t)sv0 * 64 + fl * 4);
    uint2 v = *(const uint2*)(xb + (size_t)sv1 * 64 + fl * 4);
    a0 += bl(u.x); a1 += bh(u.x); a2 += bl(u.y); a3 += bh(u.y);
    c0 += bl(v.x); c1 += bh(v.x); c2 += bl(v.y); c3 += bh(v.y);
  }
  if (i < e){
    int sv0 = srcS[i];
    uint2 u = *(const uint2*)(xb + (size_t)sv0 * 64 + fl * 4);
    a0 += bl(u.x); a1 += bh(u.x); a2 += bl(u.y); a3 += bh(u.y);
  }
  a0 += c0; a1 += c1; a2 += c2; a3 += c3;
  a0 += __shfl_xor(a0, 16); a0 += __shfl_xor(a0, 32);
  a1 += __shfl_xor(a1, 16); a1 += __shfl_xor(a1, 32);
  a2 += __shfl_xor(a2, 16); a2 += __shfl_xor(a2, 32);
  a3 += __shfl_xor(a3, 16); a3 += __shfl_xor(a3, 32);
  if (slot == 0){
    int d = e - s; if (d < 1) d = 1;
    float inv = 1.f / (float)d;
    uint2 w; w.x = packbf(a0 * inv, a1 * inv); w.y = packbf(a2 * inv, a3 * inv);
    *(uint2*)(Acat1 + (size_t)n * 128 + fl * 4) = w;
  }
}

// ---------------- SAGE layer-2 aggregation: mean of h1[src] over 2 edge-slots ----------------
// wave = 2 edge-slots x 32 lanes; each lane loads uint2 (4 bf16); unroll 2 -> 4 loads in flight
__global__ void agg2_k(const int* __restrict__ offs, const int* __restrict__ srcS, bf16* __restrict__ Acat2){
  int wid = threadIdx.x >> 6, lane = threadIdx.x & 63;
  int n = blockIdx.x * 4 + wid;
  int s = offs[n], e = offs[n + 1];
  int slot = lane >> 5, fl = lane & 31;
  float a0 = 0.f, a1 = 0.f, a2 = 0.f, a3 = 0.f;
  float c0 = 0.f, c1 = 0.f, c2 = 0.f, c3 = 0.f;
  int i = s + slot;
  for (; i + 2 < e; i += 4){
    int sv0 = srcS[i], sv1 = srcS[i + 2];
    uint2 u = *(const uint2*)(Acat2 + (size_t)sv0 * 256 + 128 + fl * 4);
    uint2 v = *(const uint2*)(Acat2 + (size_t)sv1 * 256 + 128 + fl * 4);
    a0 += bl(u.x); a1 += bh(u.x); a2 += bl(u.y); a3 += bh(u.y);
    c0 += bl(v.x); c1 += bh(v.x); c2 += bl(v.y); c3 += bh(v.y);
  }
  if (i < e){
    int sv0 = srcS[i];
    uint2 u = *(const uint2*)(Acat2 + (size_t)sv0 * 256 + 128 + fl * 4);
    a0 += bl(u.x); a1 += bh(u.x); a2 += bl(u.y); a3 += bh(u.y);
  }
  a0 += c0; a1 += c1; a2 += c2; a3 += c3;
  a0 += __shfl_xor(a0, 32);
  a1 += __shfl_xor(a1, 32);
  a2 += __shfl_xor(a2, 32);
  a3 += __shfl_xor(a3, 32);
  if (slot == 0){
    int d = e - s; if (d < 1) d = 1;
    float inv = 1.f / (float)d;
    uint2 w; w.x = packbf(a0 * inv, a1 * inv); w.y = packbf(a2 * inv, a3 * inv);
    *(uint2*)(Acat2 + (size_t)n * 256 + fl * 4) = w;
  }
}

// ---------------- generic MFMA GEMM: out[M x Ncols] = act(A[M x K] @ W[Ncols x K]^T + bias) ----------------
__global__ __launch_bounds__(256) void gemm_k(const bf16* __restrict__ A, int lda,
                                              const bf16* __restrict__ W, int K,
                                              const float* __restrict__ bias,
                                              void* __restrict__ out, int ldo, int outF32, int relu){
  __shared__ bf16 Wl[128][136];   // +8 pad: 2-way bank aliasing only
  int tid = threadIdx.x;
  int wid = tid >> 6, lane = tid & 63;
  int l16 = lane & 15, quad = lane >> 4;
  int rowBase  = blockIdx.x * 64 + wid * 16;
  int colGroup = blockIdx.y * 128;
  floatx4 acc[8] = {};
  int nStage = K >> 7;
  for (int ks = 0; ks < nStage; ++ks){
    __syncthreads();
    for (int c = tid; c < 2048; c += 256){
      int r = c >> 4, kc = (c & 15) << 3;
      *(uint4*)(&Wl[r][kc]) = *(const uint4*)(W + (size_t)(colGroup + r) * K + ks * 128 + kc);
    }
    __syncthreads();
    for (int kk = 0; kk < 4; ++kk){
      short8 af = *(const short8*)(A + (size_t)(rowBase + l16) * lda + ks * 128 + kk * 32 + quad * 8);
      #pragma unroll
      for (int c = 0; c < 8; ++c){
        short8 bq = *(const short8*)(&Wl[c * 16 + l16][kk * 32 + quad * 8]);
        acc[c] = __builtin_amdgcn_mfma_f32_16x16x32_bf16(af, bq, acc[c], 0, 0, 0);
      }
    }
  }
  #pragma unroll
  for (int c = 0; c < 8; ++c){
    int col = colGroup + c * 16 + l16;
    float bv = bias ? bias[col] : 0.f;
    #pragma unroll
    for (int r = 0; r < 4; ++r){
      int row = rowBase + quad * 4 + r;
      float v = acc[c][r] + bv;
      if (relu) v = fmaxf(v, 0.f);
      if (outF32) ((float*)out)[(size_t)row * ldo + col] = v;
      else        ((bf16*)out)[(size_t)row * ldo + col]  = __float2bfloat16(v);
    }
  }
}

// ---------------- graph mean pooling: 512 thr, 8-way row split + LDS reduce ----------------
__global__ void pool_k(const bf16* __restrict__ ne, const int* __restrict__ starts, float* __restrict__ comb){
  __shared__ float sh[8][128];
  int b = blockIdx.x;
  int q = threadIdx.x >> 6, lane = threadIdx.x & 63;   // 512 threads: 8 slots x 64 lanes
  int s = starts[b], e = starts[b + 1];
  float a0 = 0.f, a1 = 0.f;
  for (int i = s + q; i < e; i += 8){
    unsigned u = *(const unsigned*)(ne + (size_t)i * 128 + lane * 2);
    a0 += bl(u); a1 += bh(u);
  }
  sh[q][lane * 2] = a0; sh[q][lane * 2 + 1] = a1;
  __syncthreads();
  if (threadIdx.x < 128){
    int f = threadIdx.x;
    float tot = 0.f;
    #pragma unroll
    for (int k = 0; k < 8; ++k) tot += sh[k][f];
    int d = e - s; if (d < 1) d = 1;
    comb[b * 320 + f] = tot / (float)d;
  }
}

// ---------------- flow MLP: relu(flow @ Wf^T + bf), all f32 ----------------
__global__ void flow_k(const float* __restrict__ flow, const float* __restrict__ Wf,
                       const float* __restrict__ bfv, float* __restrict__ comb){
  int g = blockIdx.x * 256 + threadIdx.x;
  int b = g >> 6, j = g & 63;
  float acc = bfv[j];
  for (int k = 0; k < 16; ++k)
    acc += flow[b * 16 + k] * Wf[j * 16 + k];
  comb[b * 320 + 256 + j] = fmaxf(acc, 0.f);
}

// ---------------- gather path sequences (bf16 node_emb rows) ----------------
__global__ void gather_k(const int* __restrict__ path_idx, const bf16* __restrict__ ne, bf16* __restrict__ ps){
  int wid = threadIdx.x >> 6, lane = threadIdx.x & 63;
  int r = blockIdx.x * 4 + wid;          // r in [0, B*L)
  int idx = path_idx[r];
  ((unsigned*)ps)[(size_t)r * 64 + lane] = ((const unsigned*)ne)[(size_t)idx * 64 + lane];
}

// ---------------- LSTM recurrence: one block per batch, WhhB (bf16) in VGPRs ----------------
__global__ __launch_bounds__(256, 1) void lstm_k(const bf16* __restrict__ Whh, const float* __restrict__ pre,
                                                 const int* __restrict__ path_len, float* __restrict__ comb){
  __shared__ float h[128];
  __shared__ float g[512];
  int b = blockIdx.x, j = threadIdx.x;
  uint4 wa[16], wb[16];
  const uint4* w0 = (const uint4*)(Whh + (size_t)j * 128);
  const uint4* w1 = (const uint4*)(Whh + (size_t)(j + 256) * 128);
  #pragma unroll
  for (int k = 0; k < 16; ++k){ wa[k] = w0[k]; wb[k] = w1[k]; }
  if (j < 128) h[j] = 0.f;
  float c = 0.f, hn = 0.f;
  int len = path_len[b]; if (len < 1) len = 1; if (len > LPATH) len = LPATH;
  const float4* hv4 = (const float4*)h;
  for (int t = 0; t < len; ++t){
    __syncthreads();                                   // h ready
    float a0 = pre[((size_t)b * LPATH + t) * 512 + j];
    float a1 = pre[((size_t)b * LPATH + t) * 512 + j + 256];
    #pragma unroll
    for (int k = 0; k < 16; ++k){
      float4 h0 = hv4[2 * k], h1 = hv4[2 * k + 1];
      uint4 u = wa[k], v = wb[k];
      a0 = fmaf(bl(u.x), h0.x, a0); a0 = fmaf(bh(u.x), h0.y, a0);
      a0 = fmaf(bl(u.y), h0.z, a0); a0 = fmaf(bh(u.y), h0.w, a0);
      a0 = fmaf(bl(u.z), h1.x, a0); a0 = fmaf(bh(u.z), h1.y, a0);
      a0 = fmaf(bl(u.w), h1.z, a0); a0 = fmaf(bh(u.w), h1.w, a0);
      a1 = fmaf(bl(v.x), h0.x, a1); a1 = fmaf(bh(v.x), h0.y, a1);
      a1 = fmaf(bl(v.y), h0.z, a1); a1 = fmaf(bh(v.y), h0.w, a1);
      a1 = fmaf(bl(v.z), h1.x, a1); a1 = fmaf(bh(v.z), h1.y, a1);
      a1 = fmaf(bl(v.w), h1.z, a1); a1 = fmaf(bh(v.w), h1.w, a1);
    }
    g[j] = a0; g[j + 256] = a1;
    __syncthreads();                                   // gates ready
    if (j < 128){
      float ig = sigf(g[j]), fg = sigf(g[j + 128]);
      float gg = tanhf(g[j + 256]), og = sigf(g[j + 384]);
      c = fg * c + ig * gg;
      hn = og * tanhf(c);
      h[j] = hn;
    }
  }
  if (j < 128) comb[b * 320 + 128 + j] = hn;
}

// ---------------- scoring head (f32 weights) ----------------
__global__ void head_k(const float* __restrict__ comb, const float* __restrict__ Ws1, const float* __restrict__ bs1,
                       const float* __restrict__ Ws2, const float* __restrict__ bs2, float* __restrict__ out){
  __shared__ float cl[320];
  __shared__ float red[128];
  int b = blockIdx.x, j = threadIdx.x;   // 128 threads
  for (int k = j; k < 320; k += 128) cl[k] = comb[b * 320 + k];
  __syncthreads();
  float acc = bs1[j];
  const float4* wr = (const float4*)(Ws1 + (size_t)j * 320);
  #pragma unroll 4
  for (int kc = 0; kc < 80; ++kc){
    float4 u = wr[kc];
    int k = kc * 4;
    acc += u.x * cl[k] + u.y * cl[k + 1] + u.z * cl[k + 2] + u.w * cl[k + 3];
  }
  float hv = fmaxf(acc, 0.f);
  red[j] = hv * Ws2[j];
  __syncthreads();
  for (int s = 64; s > 0; s >>= 1){ if (j < s) red[j] += red[j + s]; __syncthreads(); }
  if (j == 0) out[b] = red[0] + bs2[0];
}

// ---------------- workspace layout (all offsets 16B-aligned) ----------------
constexpr size_t OFF_CNT    = 0;
constexpr size_t OFF_OFFS   = OFF_CNT    + 524288;     // N ints
constexpr size_t OFF_CURSOR = OFF_OFFS   + 525312;     // (N+1) ints, padded
constexpr size_t OFF_BSUM   = OFF_CURSOR + 524288;
constexpr size_t OFF_BSUMEX = OFF_BSUM   + 2048;
constexpr size_t OFF_STARTS = OFF_BSUMEX + 2048;
constexpr size_t OFF_SRCS   = OFF_STARTS + 2048;
constexpr size_t OFF_WCAT1  = OFF_SRCS   + 8388608;    // E ints
constexpr size_t OFF_WCAT2  = OFF_WCAT1  + 32768;      // 128x128 bf16
constexpr size_t OFF_WIHB   = OFF_WCAT2  + 65536;      // 128x256 bf16
constexpr size_t OFF_WHHB   = OFF_WIHB   + 131072;     // 512x128 bf16
constexpr size_t OFF_BSUMF  = OFF_WHHB   + 131072;     // 512x128 bf16
constexpr size_t OFF_COMB   = OFF_BSUMF  + 2048;       // 512 f32
constexpr size_t OFF_ACAT1  = OFF_COMB   + 327680;     // N x 128 bf16; node_emb aliases after GEMM1
constexpr size_t OFF_ACAT2  = OFF_ACAT1  + 33554432;   // N x 256 bf16 (67 MB)
// aliases into the ACAT2 region (lifetimes disjoint):
constexpr size_t OFF_PATHSEQ= OFF_ACAT2;               // 8192 x 128 bf16 (2 MB), after gemm2
constexpr size_t OFF_PRE    = OFF_ACAT2  + 2097152;    // 8192 x 512 f32 (16.8 MB), after gemm2
constexpr size_t OFF_XB     = OFF_ACAT2  + 50331648;   // N x 64 bf16 (16.8 MB), dead before gemm1 writes Acat2

extern "C" void kernel_launch(void* const* d_in, const int* in_sizes, int n_in,
                              void* d_out, int out_size, void* d_ws, size_t ws_size,
                              hipStream_t stream){
  const float* x      = (const float*)d_in[0];
  const int* edge     = (const int*)d_in[1];
  const int* batch    = (const int*)d_in[2];
  const int* path_idx = (const int*)d_in[3];
  const int* path_len = (const int*)d_in[4];
  const float* flow   = (const float*)d_in[5];
  const float* Wl1 = (const float*)d_in[6];
  const float* Wr1 = (const float*)d_in[7];
  const float* b1  = (const float*)d_in[8];
  const float* Wl2 = (const float*)d_in[9];
  const float* Wr2 = (const float*)d_in[10];
  const float* b2  = (const float*)d_in[11];
  const float* Wih = (const float*)d_in[12];
  const float* Whh = (const float*)d_in[13];
  const float* bih = (const float*)d_in[14];
  const float* bhh = (const float*)d_in[15];
  const float* Wf  = (const float*)d_in[16];
  const float* bfv = (const float*)d_in[17];
  const float* Ws1 = (const float*)d_in[18];
  const float* bs1 = (const float*)d_in[19];
  const float* Ws2 = (const float*)d_in[20];
  const float* bs2 = (const float*)d_in[21];

  char* ws = (char*)d_ws;
  int* cnt     = (int*)(ws + OFF_CNT);
  int* offs    = (int*)(ws + OFF_OFFS);
  int* cursor  = (int*)(ws + OFF_CURSOR);
  int* bsum    = (int*)(ws + OFF_BSUM);
  int* bsumEx  = (int*)(ws + OFF_BSUMEX);
  int* starts  = (int*)(ws + OFF_STARTS);
  int* srcS    = (int*)(ws + OFF_SRCS);
  bf16* Wcat1  = (bf16*)(ws + OFF_WCAT1);
  bf16* Wcat2  = (bf16*)(ws + OFF_WCAT2);
  bf16* WihB   = (bf16*)(ws + OFF_WIHB);
  bf16* WhhB   = (bf16*)(ws + OFF_WHHB);
  float* bsumF = (float*)(ws + OFF_BSUMF);
  float* comb  = (float*)(ws + OFF_COMB);
  bf16* Acat1  = (bf16*)(ws + OFF_ACAT1);
  bf16* node_emb = Acat1;                       // alias: Acat1 dead after GEMM1
  bf16* Acat2  = (bf16*)(ws + OFF_ACAT2);
  bf16* pathseq= (bf16*)(ws + OFF_PATHSEQ);     // alias: Acat2 dead after GEMM2
  float* pre   = (float*)(ws + OFF_PRE);
  bf16* xb     = (bf16*)(ws + OFF_XB);          // alias: dead before GEMM1 writes Acat2

  hipMemsetAsync(cnt, 0, N_NODES * sizeof(int), stream);
  prep_k<<<707, 256, 0, stream>>>(Wl1, Wr1, Wl2, Wr2, Wih, Whh, bih, bhh, Wcat1, Wcat2, WihB, WhhB, bsumF);
  xb16_k<<<N_NODES / 8, 256, 0, stream>>>(x, xb, Acat1);
  bounds_k<<<1, 256, 0, stream>>>(batch, starts);
  hist_k<<<N_EDGES / 256, 256, 0, stream>>>(edge + N_EDGES, cnt);
  scan1_k<<<N_NODES / 256, 256, 0, stream>>>(cnt, offs, bsum);
  scan2_k<<<1, 512, 0, stream>>>(bsum, bsumEx);
  scan3_k<<<N_NODES / 256, 256, 0, stream>>>(offs, bsumEx, cursor);
  scatter_k<<<N_EDGES / 256, 256, 0, stream>>>(edge, edge + N_EDGES, cursor, srcS);
  agg1_k<<<N_NODES / 4, 256, 0, stream>>>(xb, offs, srcS, Acat1);
  gemm_k<<<dim3(N_NODES / 64, 1), 256, 0, stream>>>(Acat1, 128, Wcat1, 128, b1, Acat2 + 128, 256, 0, 1);
  agg2_k<<<N_NODES / 4, 256, 0, stream>>>(offs, srcS, Acat2);
  gemm_k<<<dim3(N_NODES / 64, 1), 256, 0, stream>>>(Acat2, 256, Wcat2, 256, b2, node_emb, 128, 0, 1);
  pool_k<<<BATCHES, 512, 0, stream>>>(node_emb, starts, comb);
  flow_k<<<64, 256, 0, stream>>>(flow, Wf, bfv, comb);
  gather_k<<<BATCHES * LPATH / 4, 256, 0, stream>>>(path_idx, node_emb, pathseq);
  gemm_k<<<dim3(BATCHES * LPATH / 64, 4), 256, 0, stream>>>(pathseq, 128, WihB, 128, bsumF, pre, 512, 1, 0);
  lstm_k<<<BATCHES, 256, 0, stream>>>(WhhB, pre, path_len, comb);
  head_k<<<BATCHES, 128, 0, stream>>>(comb, Ws1, bs1, Ws2, bs2, (float*)d_out);
}

// Round 4
// 514.189 us; speedup vs baseline: 2.0373x; 1.3668x over previous
//
#include <hip/hip_runtime.h>
#include <hip/hip_bf16.h>

#define N_NODES 131072
#define N_EDGES 2097152
#define BATCHES 256
#define LPATH   32
// two-level counting sort params
#define NB   256          // coarse buckets (512 nodes each)
#define NPB  512          // nodes per bucket
#define GB   1024         // cntA blocks
#define EPB  2048         // edges per cntA block

typedef __hip_bfloat16 bf16;
using short8  = __attribute__((ext_vector_type(8))) short;
using floatx4 = __attribute__((ext_vector_type(4))) float;

__device__ __forceinline__ float bl(unsigned u){ union {unsigned x; float f;} c; c.x = u << 16; return c.f; }
__device__ __forceinline__ float bh(unsigned u){ union {unsigned x; float f;} c; c.x = u & 0xffff0000u; return c.f; }
__device__ __forceinline__ unsigned packbf(float lo, float hi){
  bf16 l = __float2bfloat16(lo), h = __float2bfloat16(hi);
  unsigned short lu, hu;
  __builtin_memcpy(&lu, &l, 2); __builtin_memcpy(&hu, &h, 2);
  return (unsigned)lu | ((unsigned)hu << 16);
}
__device__ __forceinline__ float sigf(float x){ return 1.f / (1.f + __expf(-x)); }

// ---------------- prep: f32 weights -> bf16 (concat along K for SAGE layers) ----------------
__global__ void prep_k(const float* __restrict__ Wl1, const float* __restrict__ Wr1,
                       const float* __restrict__ Wl2, const float* __restrict__ Wr2,
                       const float* __restrict__ Wih, const float* __restrict__ Whh,
                       const float* __restrict__ bih, const float* __restrict__ bhh,
                       bf16* __restrict__ Wcat1, bf16* __restrict__ Wcat2,
                       bf16* __restrict__ WihB, bf16* __restrict__ WhhB, float* __restrict__ bsumF){
  int g = blockIdx.x * 256 + threadIdx.x;
  if (g < 16384) {                    // Wcat1: 128 x 128 (Wl1 | Wr1), K split at 64
    int h = g >> 7, k = g & 127;
    float v = (k < 64) ? Wl1[h * 64 + k] : Wr1[h * 64 + (k - 64)];
    Wcat1[g] = __float2bfloat16(v);
  } else if (g < 49152) {             // Wcat2: 128 x 256 (Wl2 | Wr2), K split at 128
    int q = g - 16384;
    int h = q >> 8, k = q & 255;
    float v = (k < 128) ? Wl2[h * 128 + k] : Wr2[h * 128 + (k - 128)];
    Wcat2[q] = __float2bfloat16(v);
  } else if (g < 114688) {            // WihB: 512 x 128
    int q = g - 49152;
    WihB[q] = __float2bfloat16(Wih[q]);
  } else if (g < 180224) {            // WhhB: 512 x 128
    int q = g - 114688;
    WhhB[q] = __float2bfloat16(Whh[q]);
  } else if (g < 180736) {            // bsumF = bih + bhh (f32)
    int k = g - 180224;
    bsumF[k] = bih[k] + bhh[k];
  }
}

// ---------------- x (f32) -> xb (bf16) + self-half of Acat1 ----------------
__global__ void xb16_k(const float* __restrict__ x, bf16* __restrict__ xb, bf16* __restrict__ Acat1){
  int g = blockIdx.x * 256 + threadIdx.x;     // one thread per 2 features
  int n = g >> 5, p = g & 31;
  float2 v = *(const float2*)(x + (size_t)n * 64 + p * 2);
  unsigned u = packbf(v.x, v.y);
  *(unsigned*)(xb + (size_t)n * 64 + p * 2) = u;
  *(unsigned*)(Acat1 + (size_t)n * 128 + 64 + p * 2) = u;
}

// ---------------- graph segment bounds (batch is sorted) ----------------
__global__ void bounds_k(const int* __restrict__ batch, int* __restrict__ starts){
  int b = threadIdx.x;
  int lo = 0, hi = N_NODES;
  while (lo < hi){ int mid = (lo + hi) >> 1; if (batch[mid] < b) lo = mid + 1; else hi = mid; }
  starts[b] = lo;
  if (b == 0) starts[BATCHES] = N_NODES;
}

// ---------------- CSR build: two-level counting sort (no global atomics) ----------------
// pass 1: per-block LDS histogram into NB coarse buckets; counts stored bucket-major
__global__ void cntA_k(const int* __restrict__ dst, int* __restrict__ cntA){
  __shared__ int h[NB];
  int tid = threadIdx.x;
  h[tid] = 0;
  __syncthreads();
  int base = blockIdx.x * EPB;
  #pragma unroll
  for (int i = 0; i < EPB / 256; ++i){
    int d = dst[base + i * 256 + tid];
    atomicAdd(&h[d >> 9], 1);
  }
  __syncthreads();
  cntA[tid * GB + blockIdx.x] = h[tid];
}

// hierarchical exclusive scan over NB*GB counts
__global__ void scan1_k(const int* __restrict__ cnt, int* __restrict__ offs, int* __restrict__ bsum){
  __shared__ int sh[256];
  int t = threadIdx.x, i = blockIdx.x * 256 + t;
  int v = cnt[i];
  sh[t] = v; __syncthreads();
  int inc = v;
  for (int d = 1; d < 256; d <<= 1){
    int add = (t >= d) ? sh[t - d] : 0;
    __syncthreads();
    inc += add; sh[t] = inc;
    __syncthreads();
  }
  offs[i] = inc - v;
  if (t == 255) bsum[blockIdx.x] = inc;
}

__global__ void scan2_k(const int* __restrict__ bsum, int* __restrict__ bsumEx){
  __shared__ int sh[1024];
  int t = threadIdx.x;
  int v = bsum[t];
  sh[t] = v; __syncthreads();
  int inc = v;
  for (int d = 1; d < 1024; d <<= 1){
    int add = (t >= d) ? sh[t - d] : 0;
    __syncthreads();
    inc += add; sh[t] = inc;
    __syncthreads();
  }
  bsumEx[t] = inc - v;
}

__global__ void scan3_k(int* __restrict__ ofsA, const int* __restrict__ bsumEx){
  int i = blockIdx.x * 256 + threadIdx.x;
  ofsA[i] += bsumEx[i >> 8];
}

// pass 2: place packed (src | localNode<<17) into per-(bucket,block) ranges via LDS cursors
__global__ void passA2_k(const int* __restrict__ src, const int* __restrict__ dst,
                         const int* __restrict__ ofsA, unsigned* __restrict__ ebuf){
  __shared__ int cur[NB];
  int tid = threadIdx.x;
  cur[tid] = ofsA[tid * GB + blockIdx.x];
  __syncthreads();
  int base = blockIdx.x * EPB;
  #pragma unroll
  for (int i = 0; i < EPB / 256; ++i){
    int e = base + i * 256 + tid;
    int s = src[e], d = dst[e];
    int p = atomicAdd(&cur[d >> 9], 1);
    ebuf[p] = (unsigned)s | ((unsigned)(d & (NPB - 1)) << 17);
  }
}

// pass 3: one block per bucket: per-node count + LDS scan -> offs; place src into srcS (CU-local region)
__global__ void passB_k(const unsigned* __restrict__ ebuf, const int* __restrict__ ofsA,
                        int* __restrict__ offs, int* __restrict__ srcS){
  __shared__ int ncnt[NPB];
  __shared__ int pairs[256];
  __shared__ int nofs[NPB];
  int k = blockIdx.x, tid = threadIdx.x;
  int bs = ofsA[k * GB];
  int be = (k < NB - 1) ? ofsA[(k + 1) * GB] : N_EDGES;
  ncnt[tid] = 0; ncnt[tid + 256] = 0;
  __syncthreads();
  for (int i = bs + tid; i < be; i += 256)
    atomicAdd(&ncnt[ebuf[i] >> 17], 1);
  __syncthreads();
  int p = ncnt[2 * tid] + ncnt[2 * tid + 1];
  pairs[tid] = p;
  __syncthreads();
  int inc = p;
  for (int d = 1; d < 256; d <<= 1){
    int add = (tid >= d) ? pairs[tid - d] : 0;
    __syncthreads();
    inc += add; pairs[tid] = inc;
    __syncthreads();
  }
  int ex = inc - p;
  nofs[2 * tid]     = ex;
  nofs[2 * tid + 1] = ex + ncnt[2 * tid];
  __syncthreads();
  offs[k * NPB + tid]       = bs + nofs[tid];
  offs[k * NPB + tid + 256] = bs + nofs[tid + 256];
  if (k == NB - 1 && tid == 0) offs[N_NODES] = N_EDGES;
  // reuse ncnt as cursors
  ncnt[tid] = nofs[tid]; ncnt[tid + 256] = nofs[tid + 256];
  __syncthreads();
  for (int i = bs + tid; i < be; i += 256){
    unsigned w = ebuf[i];
    int loc = w >> 17, sv = w & 0x1FFFF;
    int pp = atomicAdd(&ncnt[loc], 1);
    srcS[bs + pp] = sv;
  }
}

// ---------------- SAGE layer-1 aggregation: mean of xb[src] over 4 edge-slots ----------------
__global__ void agg1_k(const bf16* __restrict__ xb, const int* __restrict__ offs,
                       const int* __restrict__ srcS, bf16* __restrict__ Acat1){
  int wid = threadIdx.x >> 6, lane = threadIdx.x & 63;
  int n = blockIdx.x * 4 + wid;
  int s = offs[n], e = offs[n + 1];
  int slot = lane >> 4, fl = lane & 15;
  float a0 = 0.f, a1 = 0.f, a2 = 0.f, a3 = 0.f;
  float c0 = 0.f, c1 = 0.f, c2 = 0.f, c3 = 0.f;
  int i = s + slot;
  for (; i + 4 < e; i += 8){
    int sv0 = srcS[i], sv1 = srcS[i + 4];
    uint2 u = *(const uint2*)(xb + (size_t)sv0 * 64 + fl * 4);
    uint2 v = *(const uint2*)(xb + (size_t)sv1 * 64 + fl * 4);
    a0 += bl(u.x); a1 += bh(u.x); a2 += bl(u.y); a3 += bh(u.y);
    c0 += bl(v.x); c1 += bh(v.x); c2 += bl(v.y); c3 += bh(v.y);
  }
  if (i < e){
    int sv0 = srcS[i];
    uint2 u = *(const uint2*)(xb + (size_t)sv0 * 64 + fl * 4);
    a0 += bl(u.x); a1 += bh(u.x); a2 += bl(u.y); a3 += bh(u.y);
  }
  a0 += c0; a1 += c1; a2 += c2; a3 += c3;
  a0 += __shfl_xor(a0, 16); a0 += __shfl_xor(a0, 32);
  a1 += __shfl_xor(a1, 16); a1 += __shfl_xor(a1, 32);
  a2 += __shfl_xor(a2, 16); a2 += __shfl_xor(a2, 32);
  a3 += __shfl_xor(a3, 16); a3 += __shfl_xor(a3, 32);
  if (slot == 0){
    int d = e - s; if (d < 1) d = 1;
    float inv = 1.f / (float)d;
    uint2 w; w.x = packbf(a0 * inv, a1 * inv); w.y = packbf(a2 * inv, a3 * inv);
    *(uint2*)(Acat1 + (size_t)n * 128 + fl * 4) = w;
  }
}

// ---------------- SAGE layer-2 aggregation: mean of h1[src] over 2 edge-slots ----------------
__global__ void agg2_k(const int* __restrict__ offs, const int* __restrict__ srcS, bf16* __restrict__ Acat2){
  int wid = threadIdx.x >> 6, lane = threadIdx.x & 63;
  int n = blockIdx.x * 4 + wid;
  int s = offs[n], e = offs[n + 1];
  int slot = lane >> 5, fl = lane & 31;
  float a0 = 0.f, a1 = 0.f, a2 = 0.f, a3 = 0.f;
  float c0 = 0.f, c1 = 0.f, c2 = 0.f, c3 = 0.f;
  int i = s + slot;
  for (; i + 2 < e; i += 4){
    int sv0 = srcS[i], sv1 = srcS[i + 2];
    uint2 u = *(const uint2*)(Acat2 + (size_t)sv0 * 256 + 128 + fl * 4);
    uint2 v = *(const uint2*)(Acat2 + (size_t)sv1 * 256 + 128 + fl * 4);
    a0 += bl(u.x); a1 += bh(u.x); a2 += bl(u.y); a3 += bh(u.y);
    c0 += bl(v.x); c1 += bh(v.x); c2 += bl(v.y); c3 += bh(v.y);
  }
  if (i < e){
    int sv0 = srcS[i];
    uint2 u = *(const uint2*)(Acat2 + (size_t)sv0 * 256 + 128 + fl * 4);
    a0 += bl(u.x); a1 += bh(u.x); a2 += bl(u.y); a3 += bh(u.y);
  }
  a0 += c0; a1 += c1; a2 += c2; a3 += c3;
  a0 += __shfl_xor(a0, 32);
  a1 += __shfl_xor(a1, 32);
  a2 += __shfl_xor(a2, 32);
  a3 += __shfl_xor(a3, 32);
  if (slot == 0){
    int d = e - s; if (d < 1) d = 1;
    float inv = 1.f / (float)d;
    uint2 w; w.x = packbf(a0 * inv, a1 * inv); w.y = packbf(a2 * inv, a3 * inv);
    *(uint2*)(Acat2 + (size_t)n * 256 + fl * 4) = w;
  }
}

// ---------------- generic MFMA GEMM: out[M x Ncols] = act(A[M x K] @ W[Ncols x K]^T + bias) ----------------
__global__ __launch_bounds__(256) void gemm_k(const bf16* __restrict__ A, int lda,
                                              const bf16* __restrict__ W, int K,
                                              const float* __restrict__ bias,
                                              void* __restrict__ out, int ldo, int outF32, int relu){
  __shared__ bf16 Wl[128][136];   // +8 pad: 2-way bank aliasing only
  int tid = threadIdx.x;
  int wid = tid >> 6, lane = tid & 63;
  int l16 = lane & 15, quad = lane >> 4;
  int rowBase  = blockIdx.x * 64 + wid * 16;
  int colGroup = blockIdx.y * 128;
  floatx4 acc[8] = {};
  int nStage = K >> 7;
  for (int ks = 0; ks < nStage; ++ks){
    __syncthreads();
    for (int c = tid; c < 2048; c += 256){
      int r = c >> 4, kc = (c & 15) << 3;
      *(uint4*)(&Wl[r][kc]) = *(const uint4*)(W + (size_t)(colGroup + r) * K + ks * 128 + kc);
    }
    __syncthreads();
    for (int kk = 0; kk < 4; ++kk){
      short8 af = *(const short8*)(A + (size_t)(rowBase + l16) * lda + ks * 128 + kk * 32 + quad * 8);
      #pragma unroll
      for (int c = 0; c < 8; ++c){
        short8 bq = *(const short8*)(&Wl[c * 16 + l16][kk * 32 + quad * 8]);
        acc[c] = __builtin_amdgcn_mfma_f32_16x16x32_bf16(af, bq, acc[c], 0, 0, 0);
      }
    }
  }
  #pragma unroll
  for (int c = 0; c < 8; ++c){
    int col = colGroup + c * 16 + l16;
    float bv = bias ? bias[col] : 0.f;
    #pragma unroll
    for (int r = 0; r < 4; ++r){
      int row = rowBase + quad * 4 + r;
      float v = acc[c][r] + bv;
      if (relu) v = fmaxf(v, 0.f);
      if (outF32) ((float*)out)[(size_t)row * ldo + col] = v;
      else        ((bf16*)out)[(size_t)row * ldo + col]  = __float2bfloat16(v);
    }
  }
}

// ---------------- graph mean pooling: 512 thr, 8-way row split + LDS reduce ----------------
__global__ void pool_k(const bf16* __restrict__ ne, const int* __restrict__ starts, float* __restrict__ comb){
  __shared__ float sh[8][128];
  int b = blockIdx.x;
  int q = threadIdx.x >> 6, lane = threadIdx.x & 63;   // 512 threads: 8 slots x 64 lanes
  int s = starts[b], e = starts[b + 1];
  float a0 = 0.f, a1 = 0.f;
  for (int i = s + q; i < e; i += 8){
    unsigned u = *(const unsigned*)(ne + (size_t)i * 128 + lane * 2);
    a0 += bl(u); a1 += bh(u);
  }
  sh[q][lane * 2] = a0; sh[q][lane * 2 + 1] = a1;
  __syncthreads();
  if (threadIdx.x < 128){
    int f = threadIdx.x;
    float tot = 0.f;
    #pragma unroll
    for (int k = 0; k < 8; ++k) tot += sh[k][f];
    int d = e - s; if (d < 1) d = 1;
    comb[b * 320 + f] = tot / (float)d;
  }
}

// ---------------- flow MLP: relu(flow @ Wf^T + bf), all f32 ----------------
__global__ void flow_k(const float* __restrict__ flow, const float* __restrict__ Wf,
                       const float* __restrict__ bfv, float* __restrict__ comb){
  int g = blockIdx.x * 256 + threadIdx.x;
  int b = g >> 6, j = g & 63;
  float acc = bfv[j];
  for (int k = 0; k < 16; ++k)
    acc += flow[b * 16 + k] * Wf[j * 16 + k];
  comb[b * 320 + 256 + j] = fmaxf(acc, 0.f);
}

// ---------------- gather path sequences (bf16 node_emb rows) ----------------
__global__ void gather_k(const int* __restrict__ path_idx, const bf16* __restrict__ ne, bf16* __restrict__ ps){
  int wid = threadIdx.x >> 6, lane = threadIdx.x & 63;
  int r = blockIdx.x * 4 + wid;          // r in [0, B*L)
  int idx = path_idx[r];
  ((unsigned*)ps)[(size_t)r * 64 + lane] = ((const unsigned*)ne)[(size_t)idx * 64 + lane];
}

// ---------------- LSTM recurrence: one block per batch, WhhB (bf16) in VGPRs ----------------
__global__ __launch_bounds__(256, 1) void lstm_k(const bf16* __restrict__ Whh, const float* __restrict__ pre,
                                                 const int* __restrict__ path_len, float* __restrict__ comb){
  __shared__ float h[128];
  __shared__ float g[512];
  int b = blockIdx.x, j = threadIdx.x;
  uint4 wa[16], wb[16];
  const uint4* w0 = (const uint4*)(Whh + (size_t)j * 128);
  const uint4* w1 = (const uint4*)(Whh + (size_t)(j + 256) * 128);
  #pragma unroll
  for (int k = 0; k < 16; ++k){ wa[k] = w0[k]; wb[k] = w1[k]; }
  if (j < 128) h[j] = 0.f;
  float c = 0.f, hn = 0.f;
  int len = path_len[b]; if (len < 1) len = 1; if (len > LPATH) len = LPATH;
  const float4* hv4 = (const float4*)h;
  for (int t = 0; t < len; ++t){
    __syncthreads();                                   // h ready
    float a0 = pre[((size_t)b * LPATH + t) * 512 + j];
    float a1 = pre[((size_t)b * LPATH + t) * 512 + j + 256];
    #pragma unroll
    for (int k = 0; k < 16; ++k){
      float4 h0 = hv4[2 * k], h1 = hv4[2 * k + 1];
      uint4 u = wa[k], v = wb[k];
      a0 = fmaf(bl(u.x), h0.x, a0); a0 = fmaf(bh(u.x), h0.y, a0);
      a0 = fmaf(bl(u.y), h0.z, a0); a0 = fmaf(bh(u.y), h0.w, a0);
      a0 = fmaf(bl(u.z), h1.x, a0); a0 = fmaf(bh(u.z), h1.y, a0);
      a0 = fmaf(bl(u.w), h1.z, a0); a0 = fmaf(bh(u.w), h1.w, a0);
      a1 = fmaf(bl(v.x), h0.x, a1); a1 = fmaf(bh(v.x), h0.y, a1);
      a1 = fmaf(bl(v.y), h0.z, a1); a1 = fmaf(bh(v.y), h0.w, a1);
      a1 = fmaf(bl(v.z), h1.x, a1); a1 = fmaf(bh(v.z), h1.y, a1);
      a1 = fmaf(bl(v.w), h1.z, a1); a1 = fmaf(bh(v.w), h1.w, a1);
    }
    g[j] = a0; g[j + 256] = a1;
    __syncthreads();                                   // gates ready
    if (j < 128){
      float ig = sigf(g[j]), fg = sigf(g[j + 128]);
      float gg = tanhf(g[j + 256]), og = sigf(g[j + 384]);
      c = fg * c + ig * gg;
      hn = og * tanhf(c);
      h[j] = hn;
    }
  }
  if (j < 128) comb[b * 320 + 128 + j] = hn;
}

// ---------------- scoring head (f32 weights) ----------------
__global__ void head_k(const float* __restrict__ comb, const float* __restrict__ Ws1, const float* __restrict__ bs1,
                       const float* __restrict__ Ws2, const float* __restrict__ bs2, float* __restrict__ out){
  __shared__ float cl[320];
  __shared__ float red[128];
  int b = blockIdx.x, j = threadIdx.x;   // 128 threads
  for (int k = j; k < 320; k += 128) cl[k] = comb[b * 320 + k];
  __syncthreads();
  float acc = bs1[j];
  const float4* wr = (const float4*)(Ws1 + (size_t)j * 320);
  #pragma unroll 4
  for (int kc = 0; kc < 80; ++kc){
    float4 u = wr[kc];
    int k = kc * 4;
    acc += u.x * cl[k] + u.y * cl[k + 1] + u.z * cl[k + 2] + u.w * cl[k + 3];
  }
  float hv = fmaxf(acc, 0.f);
  red[j] = hv * Ws2[j];
  __syncthreads();
  for (int s = 64; s > 0; s >>= 1){ if (j < s) red[j] += red[j + s]; __syncthreads(); }
  if (j == 0) out[b] = red[0] + bs2[0];
}

// ---------------- workspace layout (16B-aligned) ----------------
constexpr size_t OFF_OFFS   = 0;                       // (N+1) ints
constexpr size_t OFF_CNTA   = 524544;                  // NB*GB ints = 1 MB
constexpr size_t OFF_OFSA   = OFF_CNTA   + 1048576;    // NB*GB ints = 1 MB
constexpr size_t OFF_BSUM   = OFF_OFSA   + 1048576;    // 1024 ints
constexpr size_t OFF_BSUMEX = OFF_BSUM   + 4096;       // 1024 ints
constexpr size_t OFF_STARTS = OFF_BSUMEX + 4096;       // 257 ints
constexpr size_t OFF_SRCS   = OFF_STARTS + 2048;       // E ints = 8.4 MB
constexpr size_t OFF_WCAT1  = OFF_SRCS   + 8388608;
constexpr size_t OFF_WCAT2  = OFF_WCAT1  + 32768;
constexpr size_t OFF_WIHB   = OFF_WCAT2  + 65536;
constexpr size_t OFF_WHHB   = OFF_WIHB   + 131072;
constexpr size_t OFF_BSUMF  = OFF_WHHB   + 131072;
constexpr size_t OFF_COMB   = OFF_BSUMF  + 2048;
constexpr size_t OFF_ACAT1  = OFF_COMB   + 327680;     // N x 128 bf16; node_emb aliases after GEMM1
constexpr size_t OFF_ACAT2  = OFF_ACAT1  + 33554432;   // N x 256 bf16 (67 MB)
// aliases into the ACAT2 region (lifetimes disjoint):
constexpr size_t OFF_EBUF   = OFF_ACAT2;               // E unsigned (8.4 MB), dead before gemm1
constexpr size_t OFF_PATHSEQ= OFF_ACAT2;               // 8192 x 128 bf16, after gemm2
constexpr size_t OFF_PRE    = OFF_ACAT2  + 2097152;    // 8192 x 512 f32, after gemm2
constexpr size_t OFF_XB     = OFF_ACAT2  + 50331648;   // N x 64 bf16, dead before gemm1 writes Acat2

extern "C" void kernel_launch(void* const* d_in, const int* in_sizes, int n_in,
                              void* d_out, int out_size, void* d_ws, size_t ws_size,
                              hipStream_t stream){
  const float* x      = (const float*)d_in[0];
  const int* edge     = (const int*)d_in[1];
  const int* batch    = (const int*)d_in[2];
  const int* path_idx = (const int*)d_in[3];
  const int* path_len = (const int*)d_in[4];
  const float* flow   = (const float*)d_in[5];
  const float* Wl1 = (const float*)d_in[6];
  const float* Wr1 = (const float*)d_in[7];
  const float* b1  = (const float*)d_in[8];
  const float* Wl2 = (const float*)d_in[9];
  const float* Wr2 = (const float*)d_in[10];
  const float* b2  = (const float*)d_in[11];
  const float* Wih = (const float*)d_in[12];
  const float* Whh = (const float*)d_in[13];
  const float* bih = (const float*)d_in[14];
  const float* bhh = (const float*)d_in[15];
  const float* Wf  = (const float*)d_in[16];
  const float* bfv = (const float*)d_in[17];
  const float* Ws1 = (const float*)d_in[18];
  const float* bs1 = (const float*)d_in[19];
  const float* Ws2 = (const float*)d_in[20];
  const float* bs2 = (const float*)d_in[21];

  char* ws = (char*)d_ws;
  int* offs    = (int*)(ws + OFF_OFFS);
  int* cntA    = (int*)(ws + OFF_CNTA);
  int* ofsA    = (int*)(ws + OFF_OFSA);
  int* bsum    = (int*)(ws + OFF_BSUM);
  int* bsumEx  = (int*)(ws + OFF_BSUMEX);
  int* starts  = (int*)(ws + OFF_STARTS);
  int* srcS    = (int*)(ws + OFF_SRCS);
  bf16* Wcat1  = (bf16*)(ws + OFF_WCAT1);
  bf16* Wcat2  = (bf16*)(ws + OFF_WCAT2);
  bf16* WihB   = (bf16*)(ws + OFF_WIHB);
  bf16* WhhB   = (bf16*)(ws + OFF_WHHB);
  float* bsumF = (float*)(ws + OFF_BSUMF);
  float* comb  = (float*)(ws + OFF_COMB);
  bf16* Acat1  = (bf16*)(ws + OFF_ACAT1);
  bf16* node_emb = Acat1;                       // alias: Acat1 dead after GEMM1
  bf16* Acat2  = (bf16*)(ws + OFF_ACAT2);
  unsigned* ebuf = (unsigned*)(ws + OFF_EBUF);  // alias: dead before GEMM1 writes Acat2
  bf16* pathseq= (bf16*)(ws + OFF_PATHSEQ);     // alias: Acat2 dead after GEMM2
  float* pre   = (float*)(ws + OFF_PRE);
  bf16* xb     = (bf16*)(ws + OFF_XB);          // alias: dead before GEMM1 writes Acat2

  prep_k<<<707, 256, 0, stream>>>(Wl1, Wr1, Wl2, Wr2, Wih, Whh, bih, bhh, Wcat1, Wcat2, WihB, WhhB, bsumF);
  xb16_k<<<N_NODES / 8, 256, 0, stream>>>(x, xb, Acat1);
  bounds_k<<<1, 256, 0, stream>>>(batch, starts);
  cntA_k<<<GB, 256, 0, stream>>>(edge + N_EDGES, cntA);
  scan1_k<<<NB * GB / 256, 256, 0, stream>>>(cntA, ofsA, bsum);
  scan2_k<<<1, 1024, 0, stream>>>(bsum, bsumEx);
  scan3_k<<<NB * GB / 256, 256, 0, stream>>>(ofsA, bsumEx);
  passA2_k<<<GB, 256, 0, stream>>>(edge, edge + N_EDGES, ofsA, ebuf);
  passB_k<<<NB, 256, 0, stream>>>(ebuf, ofsA, offs, srcS);
  agg1_k<<<N_NODES / 4, 256, 0, stream>>>(xb, offs, srcS, Acat1);
  gemm_k<<<dim3(N_NODES / 64, 1), 256, 0, stream>>>(Acat1, 128, Wcat1, 128, b1, Acat2 + 128, 256, 0, 1);
  agg2_k<<<N_NODES / 4, 256, 0, stream>>>(offs, srcS, Acat2);
  gemm_k<<<dim3(N_NODES / 64, 1), 256, 0, stream>>>(Acat2, 256, Wcat2, 256, b2, node_emb, 128, 0, 1);
  pool_k<<<BATCHES, 512, 0, stream>>>(node_emb, starts, comb);
  flow_k<<<64, 256, 0, stream>>>(flow, Wf, bfv, comb);
  gather_k<<<BATCHES * LPATH / 4, 256, 0, stream>>>(path_idx, node_emb, pathseq);
  gemm_k<<<dim3(BATCHES * LPATH / 64, 4), 256, 0, stream>>>(pathseq, 128, WihB, 128, bsumF, pre, 512, 1, 0);
  lstm_k<<<BATCHES, 256, 0, stream>>>(WhhB, pre, path_len, comb);
  head_k<<<BATCHES, 128, 0, stream>>>(comb, Ws1, bs1, Ws2, bs2, (float*)d_out);
}

// Round 5
// 486.370 us; speedup vs baseline: 2.1538x; 1.0572x over previous
//
#include <hip/hip_runtime.h>
#include <hip/hip_bf16.h>

#define N_NODES 131072
#define N_EDGES 2097152
#define BATCHES 256
#define LPATH   32
// two-level counting sort params
#define NB   256          // coarse buckets (512 nodes each)
#define NPB  512          // nodes per bucket
#define GB   256          // cntA/passA2 blocks
#define EPB  8192         // edges per block

typedef __hip_bfloat16 bf16;
using short8  = __attribute__((ext_vector_type(8))) short;
using floatx4 = __attribute__((ext_vector_type(4))) float;

__device__ __forceinline__ float bl(unsigned u){ union {unsigned x; float f;} c; c.x = u << 16; return c.f; }
__device__ __forceinline__ float bh(unsigned u){ union {unsigned x; float f;} c; c.x = u & 0xffff0000u; return c.f; }
__device__ __forceinline__ unsigned packbf(float lo, float hi){
  bf16 l = __float2bfloat16(lo), h = __float2bfloat16(hi);
  unsigned short lu, hu;
  __builtin_memcpy(&lu, &l, 2); __builtin_memcpy(&hu, &h, 2);
  return (unsigned)lu | ((unsigned)hu << 16);
}
__device__ __forceinline__ float sigf(float x){ return 1.f / (1.f + __expf(-x)); }

// ---------------- prep: f32 weights -> bf16 (concat along K for SAGE layers) ----------------
__global__ void prep_k(const float* __restrict__ Wl1, const float* __restrict__ Wr1,
                       const float* __restrict__ Wl2, const float* __restrict__ Wr2,
                       const float* __restrict__ Wih, const float* __restrict__ Whh,
                       const float* __restrict__ bih, const float* __restrict__ bhh,
                       bf16* __restrict__ Wcat1, bf16* __restrict__ Wcat2,
                       bf16* __restrict__ WihB, bf16* __restrict__ WhhB, float* __restrict__ bsumF){
  int g = blockIdx.x * 256 + threadIdx.x;
  if (g < 16384) {                    // Wcat1: 128 x 128 (Wl1 | Wr1), K split at 64
    int h = g >> 7, k = g & 127;
    float v = (k < 64) ? Wl1[h * 64 + k] : Wr1[h * 64 + (k - 64)];
    Wcat1[g] = __float2bfloat16(v);
  } else if (g < 49152) {             // Wcat2: 128 x 256 (Wl2 | Wr2), K split at 128
    int q = g - 16384;
    int h = q >> 8, k = q & 255;
    float v = (k < 128) ? Wl2[h * 128 + k] : Wr2[h * 128 + (k - 128)];
    Wcat2[q] = __float2bfloat16(v);
  } else if (g < 114688) {            // WihB: 512 x 128
    int q = g - 49152;
    WihB[q] = __float2bfloat16(Wih[q]);
  } else if (g < 180224) {            // WhhB: 512 x 128
    int q = g - 114688;
    WhhB[q] = __float2bfloat16(Whh[q]);
  } else if (g < 180736) {            // bsumF = bih + bhh (f32)
    int k = g - 180224;
    bsumF[k] = bih[k] + bhh[k];
  }
}

// ---------------- x (f32) -> xb (bf16) + self-half of Acat1 ----------------
__global__ void xb16_k(const float* __restrict__ x, bf16* __restrict__ xb, bf16* __restrict__ Acat1){
  int g = blockIdx.x * 256 + threadIdx.x;     // one thread per 2 features
  int n = g >> 5, p = g & 31;
  float2 v = *(const float2*)(x + (size_t)n * 64 + p * 2);
  unsigned u = packbf(v.x, v.y);
  *(unsigned*)(xb + (size_t)n * 64 + p * 2) = u;
  *(unsigned*)(Acat1 + (size_t)n * 128 + 64 + p * 2) = u;
}

// ---------------- graph segment bounds (batch is sorted) ----------------
__global__ void bounds_k(const int* __restrict__ batch, int* __restrict__ starts){
  int b = threadIdx.x;
  int lo = 0, hi = N_NODES;
  while (lo < hi){ int mid = (lo + hi) >> 1; if (batch[mid] < b) lo = mid + 1; else hi = mid; }
  starts[b] = lo;
  if (b == 0) starts[BATCHES] = N_NODES;
}

// ---------------- CSR build: two-level counting sort (no global atomics) ----------------
// pass 1: per-block LDS histogram into NB coarse buckets; counts stored bucket-major
__global__ void cntA_k(const int* __restrict__ dst, int* __restrict__ cntA){
  __shared__ int h[NB];
  int tid = threadIdx.x;
  h[tid] = 0;
  __syncthreads();
  int base = blockIdx.x * EPB;
  #pragma unroll
  for (int i = 0; i < EPB / 256; ++i){
    int d = dst[base + i * 256 + tid];
    atomicAdd(&h[d >> 9], 1);
  }
  __syncthreads();
  cntA[tid * GB + blockIdx.x] = h[tid];
}

// per-bucket exclusive scan (one block per bucket, 256 entries each) + bucket totals
__global__ void scan1_k(const int* __restrict__ cnt, int* __restrict__ ofsA, int* __restrict__ bsum){
  __shared__ int sh[256];
  int t = threadIdx.x, i = blockIdx.x * 256 + t;
  int v = cnt[i];
  sh[t] = v; __syncthreads();
  int inc = v;
  for (int d = 1; d < 256; d <<= 1){
    int add = (t >= d) ? sh[t - d] : 0;
    __syncthreads();
    inc += add; sh[t] = inc;
    __syncthreads();
  }
  ofsA[i] = inc - v;
  if (t == 255) bsum[blockIdx.x] = inc;
}

// exclusive scan of the NB bucket totals
__global__ void scan2_k(const int* __restrict__ bsum, int* __restrict__ bsumEx){
  __shared__ int sh[NB];
  int t = threadIdx.x;
  int v = bsum[t];
  sh[t] = v; __syncthreads();
  int inc = v;
  for (int d = 1; d < NB; d <<= 1){
    int add = (t >= d) ? sh[t - d] : 0;
    __syncthreads();
    inc += add; sh[t] = inc;
    __syncthreads();
  }
  bsumEx[t] = inc - v;
}

// pass 2: place packed (src | localNode<<17) into per-(bucket,block) ranges via LDS cursors
__global__ void passA2_k(const int* __restrict__ src, const int* __restrict__ dst,
                         const int* __restrict__ ofsA, const int* __restrict__ bsumEx,
                         unsigned* __restrict__ ebuf){
  __shared__ int cur[NB];
  int tid = threadIdx.x;
  cur[tid] = ofsA[tid * GB + blockIdx.x] + bsumEx[tid];
  __syncthreads();
  int base = blockIdx.x * EPB;
  #pragma unroll
  for (int i = 0; i < EPB / 256; ++i){
    int e = base + i * 256 + tid;
    int s = src[e], d = dst[e];
    int p = atomicAdd(&cur[d >> 9], 1);
    ebuf[p] = (unsigned)s | ((unsigned)(d & (NPB - 1)) << 17);
  }
}

// pass 3: one block per bucket: per-node count + LDS scan -> offs; place src into srcS (CU-local region)
__global__ void passB_k(const unsigned* __restrict__ ebuf, const int* __restrict__ bsumEx,
                        int* __restrict__ offs, int* __restrict__ srcS){
  __shared__ int ncnt[NPB];
  __shared__ int pairs[256];
  __shared__ int nofs[NPB];
  int k = blockIdx.x, tid = threadIdx.x;
  int bs = bsumEx[k];
  int be = (k < NB - 1) ? bsumEx[k + 1] : N_EDGES;
  ncnt[tid] = 0; ncnt[tid + 256] = 0;
  __syncthreads();
  for (int i = bs + tid; i < be; i += 256)
    atomicAdd(&ncnt[ebuf[i] >> 17], 1);
  __syncthreads();
  int p = ncnt[2 * tid] + ncnt[2 * tid + 1];
  pairs[tid] = p;
  __syncthreads();
  int inc = p;
  for (int d = 1; d < 256; d <<= 1){
    int add = (tid >= d) ? pairs[tid - d] : 0;
    __syncthreads();
    inc += add; pairs[tid] = inc;
    __syncthreads();
  }
  int ex = inc - p;
  nofs[2 * tid]     = ex;
  nofs[2 * tid + 1] = ex + ncnt[2 * tid];
  __syncthreads();
  offs[k * NPB + tid]       = bs + nofs[tid];
  offs[k * NPB + tid + 256] = bs + nofs[tid + 256];
  if (k == NB - 1 && tid == 0) offs[N_NODES] = N_EDGES;
  // reuse ncnt as cursors
  ncnt[tid] = nofs[tid]; ncnt[tid + 256] = nofs[tid + 256];
  __syncthreads();
  for (int i = bs + tid; i < be; i += 256){
    unsigned w = ebuf[i];
    int loc = w >> 17, sv = w & 0x1FFFF;
    int pp = atomicAdd(&ncnt[loc], 1);
    srcS[bs + pp] = sv;
  }
}

// ---------------- SAGE layer-1 aggregation: mean of xb[src], 8 edge-slots x 8 lanes x uint4 ----------------
__global__ void agg1_k(const bf16* __restrict__ xb, const int* __restrict__ offs,
                       const int* __restrict__ srcS, bf16* __restrict__ Acat1){
  int wid = threadIdx.x >> 6, lane = threadIdx.x & 63;
  int n = blockIdx.x * 4 + wid;
  int s = offs[n], e = offs[n + 1];
  int slot = lane >> 3, fl = lane & 7;
  float a0=0,a1=0,a2=0,a3=0,a4=0,a5=0,a6=0,a7=0;
  float c0=0,c1=0,c2=0,c3=0,c4=0,c5=0,c6=0,c7=0;
  int i = s + slot;
  for (; i + 8 < e; i += 16){
    int sv0 = srcS[i], sv1 = srcS[i + 8];
    uint4 u = *(const uint4*)(xb + (size_t)sv0 * 64 + fl * 8);
    uint4 v = *(const uint4*)(xb + (size_t)sv1 * 64 + fl * 8);
    a0 += bl(u.x); a1 += bh(u.x); a2 += bl(u.y); a3 += bh(u.y);
    a4 += bl(u.z); a5 += bh(u.z); a6 += bl(u.w); a7 += bh(u.w);
    c0 += bl(v.x); c1 += bh(v.x); c2 += bl(v.y); c3 += bh(v.y);
    c4 += bl(v.z); c5 += bh(v.z); c6 += bl(v.w); c7 += bh(v.w);
  }
  if (i < e){
    int sv0 = srcS[i];
    uint4 u = *(const uint4*)(xb + (size_t)sv0 * 64 + fl * 8);
    a0 += bl(u.x); a1 += bh(u.x); a2 += bl(u.y); a3 += bh(u.y);
    a4 += bl(u.z); a5 += bh(u.z); a6 += bl(u.w); a7 += bh(u.w);
  }
  a0 += c0; a1 += c1; a2 += c2; a3 += c3;
  a4 += c4; a5 += c5; a6 += c6; a7 += c7;
  a0 += __shfl_xor(a0, 8); a0 += __shfl_xor(a0, 16); a0 += __shfl_xor(a0, 32);
  a1 += __shfl_xor(a1, 8); a1 += __shfl_xor(a1, 16); a1 += __shfl_xor(a1, 32);
  a2 += __shfl_xor(a2, 8); a2 += __shfl_xor(a2, 16); a2 += __shfl_xor(a2, 32);
  a3 += __shfl_xor(a3, 8); a3 += __shfl_xor(a3, 16); a3 += __shfl_xor(a3, 32);
  a4 += __shfl_xor(a4, 8); a4 += __shfl_xor(a4, 16); a4 += __shfl_xor(a4, 32);
  a5 += __shfl_xor(a5, 8); a5 += __shfl_xor(a5, 16); a5 += __shfl_xor(a5, 32);
  a6 += __shfl_xor(a6, 8); a6 += __shfl_xor(a6, 16); a6 += __shfl_xor(a6, 32);
  a7 += __shfl_xor(a7, 8); a7 += __shfl_xor(a7, 16); a7 += __shfl_xor(a7, 32);
  if (slot == 0){
    int d = e - s; if (d < 1) d = 1;
    float inv = 1.f / (float)d;
    uint4 w;
    w.x = packbf(a0 * inv, a1 * inv); w.y = packbf(a2 * inv, a3 * inv);
    w.z = packbf(a4 * inv, a5 * inv); w.w = packbf(a6 * inv, a7 * inv);
    *(uint4*)(Acat1 + (size_t)n * 128 + fl * 8) = w;
  }
}

// ---------------- SAGE layer-2 aggregation: mean of h1[src], 4 edge-slots x 16 lanes x uint4 ----------------
__global__ void agg2_k(const int* __restrict__ offs, const int* __restrict__ srcS, bf16* __restrict__ Acat2){
  int wid = threadIdx.x >> 6, lane = threadIdx.x & 63;
  int n = blockIdx.x * 4 + wid;
  int s = offs[n], e = offs[n + 1];
  int slot = lane >> 4, fl = lane & 15;
  float a0=0,a1=0,a2=0,a3=0,a4=0,a5=0,a6=0,a7=0;
  float c0=0,c1=0,c2=0,c3=0,c4=0,c5=0,c6=0,c7=0;
  int i = s + slot;
  for (; i + 4 < e; i += 8){
    int sv0 = srcS[i], sv1 = srcS[i + 4];
    uint4 u = *(const uint4*)(Acat2 + (size_t)sv0 * 256 + 128 + fl * 8);
    uint4 v = *(const uint4*)(Acat2 + (size_t)sv1 * 256 + 128 + fl * 8);
    a0 += bl(u.x); a1 += bh(u.x); a2 += bl(u.y); a3 += bh(u.y);
    a4 += bl(u.z); a5 += bh(u.z); a6 += bl(u.w); a7 += bh(u.w);
    c0 += bl(v.x); c1 += bh(v.x); c2 += bl(v.y); c3 += bh(v.y);
    c4 += bl(v.z); c5 += bh(v.z); c6 += bl(v.w); c7 += bh(v.w);
  }
  if (i < e){
    int sv0 = srcS[i];
    uint4 u = *(const uint4*)(Acat2 + (size_t)sv0 * 256 + 128 + fl * 8);
    a0 += bl(u.x); a1 += bh(u.x); a2 += bl(u.y); a3 += bh(u.y);
    a4 += bl(u.z); a5 += bh(u.z); a6 += bl(u.w); a7 += bh(u.w);
  }
  a0 += c0; a1 += c1; a2 += c2; a3 += c3;
  a4 += c4; a5 += c5; a6 += c6; a7 += c7;
  a0 += __shfl_xor(a0, 16); a0 += __shfl_xor(a0, 32);
  a1 += __shfl_xor(a1, 16); a1 += __shfl_xor(a1, 32);
  a2 += __shfl_xor(a2, 16); a2 += __shfl_xor(a2, 32);
  a3 += __shfl_xor(a3, 16); a3 += __shfl_xor(a3, 32);
  a4 += __shfl_xor(a4, 16); a4 += __shfl_xor(a4, 32);
  a5 += __shfl_xor(a5, 16); a5 += __shfl_xor(a5, 32);
  a6 += __shfl_xor(a6, 16); a6 += __shfl_xor(a6, 32);
  a7 += __shfl_xor(a7, 16); a7 += __shfl_xor(a7, 32);
  if (slot == 0){
    int d = e - s; if (d < 1) d = 1;
    float inv = 1.f / (float)d;
    uint4 w;
    w.x = packbf(a0 * inv, a1 * inv); w.y = packbf(a2 * inv, a3 * inv);
    w.z = packbf(a4 * inv, a5 * inv); w.w = packbf(a6 * inv, a7 * inv);
    *(uint4*)(Acat2 + (size_t)n * 256 + fl * 8) = w;
  }
}

// ---------------- generic MFMA GEMM: out[M x Ncols] = act(A[M x K] @ W[Ncols x K]^T + bias) ----------------
__global__ __launch_bounds__(256) void gemm_k(const bf16* __restrict__ A, int lda,
                                              const bf16* __restrict__ W, int K,
                                              const float* __restrict__ bias,
                                              void* __restrict__ out, int ldo, int outF32, int relu){
  __shared__ bf16 Wl[128][136];   // +8 pad: 2-way bank aliasing only
  int tid = threadIdx.x;
  int wid = tid >> 6, lane = tid & 63;
  int l16 = lane & 15, quad = lane >> 4;
  int rowBase  = blockIdx.x * 64 + wid * 16;
  int colGroup = blockIdx.y * 128;
  floatx4 acc[8] = {};
  int nStage = K >> 7;
  for (int ks = 0; ks < nStage; ++ks){
    __syncthreads();
    for (int c = tid; c < 2048; c += 256){
      int r = c >> 4, kc = (c & 15) << 3;
      *(uint4*)(&Wl[r][kc]) = *(const uint4*)(W + (size_t)(colGroup + r) * K + ks * 128 + kc);
    }
    __syncthreads();
    for (int kk = 0; kk < 4; ++kk){
      short8 af = *(const short8*)(A + (size_t)(rowBase + l16) * lda + ks * 128 + kk * 32 + quad * 8);
      #pragma unroll
      for (int c = 0; c < 8; ++c){
        short8 bq = *(const short8*)(&Wl[c * 16 + l16][kk * 32 + quad * 8]);
        acc[c] = __builtin_amdgcn_mfma_f32_16x16x32_bf16(af, bq, acc[c], 0, 0, 0);
      }
    }
  }
  #pragma unroll
  for (int c = 0; c < 8; ++c){
    int col = colGroup + c * 16 + l16;
    float bv = bias ? bias[col] : 0.f;
    #pragma unroll
    for (int r = 0; r < 4; ++r){
      int row = rowBase + quad * 4 + r;
      float v = acc[c][r] + bv;
      if (relu) v = fmaxf(v, 0.f);
      if (outF32) ((float*)out)[(size_t)row * ldo + col] = v;
      else        ((bf16*)out)[(size_t)row * ldo + col]  = __float2bfloat16(v);
    }
  }
}

// ---------------- graph mean pooling: 512 thr, 8-way row split + LDS reduce ----------------
__global__ void pool_k(const bf16* __restrict__ ne, const int* __restrict__ starts, float* __restrict__ comb){
  __shared__ float sh[8][128];
  int b = blockIdx.x;
  int q = threadIdx.x >> 6, lane = threadIdx.x & 63;   // 512 threads: 8 slots x 64 lanes
  int s = starts[b], e = starts[b + 1];
  float a0 = 0.f, a1 = 0.f;
  for (int i = s + q; i < e; i += 8){
    unsigned u = *(const unsigned*)(ne + (size_t)i * 128 + lane * 2);
    a0 += bl(u); a1 += bh(u);
  }
  sh[q][lane * 2] = a0; sh[q][lane * 2 + 1] = a1;
  __syncthreads();
  if (threadIdx.x < 128){
    int f = threadIdx.x;
    float tot = 0.f;
    #pragma unroll
    for (int k = 0; k < 8; ++k) tot += sh[k][f];
    int d = e - s; if (d < 1) d = 1;
    comb[b * 320 + f] = tot / (float)d;
  }
}

// ---------------- flow MLP: relu(flow @ Wf^T + bf), all f32 ----------------
__global__ void flow_k(const float* __restrict__ flow, const float* __restrict__ Wf,
                       const float* __restrict__ bfv, float* __restrict__ comb){
  int g = blockIdx.x * 256 + threadIdx.x;
  int b = g >> 6, j = g & 63;
  float acc = bfv[j];
  for (int k = 0; k < 16; ++k)
    acc += flow[b * 16 + k] * Wf[j * 16 + k];
  comb[b * 320 + 256 + j] = fmaxf(acc, 0.f);
}

// ---------------- gather path sequences (bf16 node_emb rows) ----------------
__global__ void gather_k(const int* __restrict__ path_idx, const bf16* __restrict__ ne, bf16* __restrict__ ps){
  int wid = threadIdx.x >> 6, lane = threadIdx.x & 63;
  int r = blockIdx.x * 4 + wid;          // r in [0, B*L)
  int idx = path_idx[r];
  ((unsigned*)ps)[(size_t)r * 64 + lane] = ((const unsigned*)ne)[(size_t)idx * 64 + lane];
}

// ---------------- LSTM recurrence: one block per batch, WhhB (bf16) in VGPRs ----------------
__global__ __launch_bounds__(256, 1) void lstm_k(const bf16* __restrict__ Whh, const float* __restrict__ pre,
                                                 const int* __restrict__ path_len, float* __restrict__ comb){
  __shared__ float h[128];
  __shared__ float g[512];
  int b = blockIdx.x, j = threadIdx.x;
  uint4 wa[16], wb[16];
  const uint4* w0 = (const uint4*)(Whh + (size_t)j * 128);
  const uint4* w1 = (const uint4*)(Whh + (size_t)(j + 256) * 128);
  #pragma unroll
  for (int k = 0; k < 16; ++k){ wa[k] = w0[k]; wb[k] = w1[k]; }
  if (j < 128) h[j] = 0.f;
  float c = 0.f, hn = 0.f;
  int len = path_len[b]; if (len < 1) len = 1; if (len > LPATH) len = LPATH;
  const float4* hv4 = (const float4*)h;
  for (int t = 0; t < len; ++t){
    __syncthreads();                                   // h ready
    float a0 = pre[((size_t)b * LPATH + t) * 512 + j];
    float a1 = pre[((size_t)b * LPATH + t) * 512 + j + 256];
    #pragma unroll
    for (int k = 0; k < 16; ++k){
      float4 h0 = hv4[2 * k], h1 = hv4[2 * k + 1];
      uint4 u = wa[k], v = wb[k];
      a0 = fmaf(bl(u.x), h0.x, a0); a0 = fmaf(bh(u.x), h0.y, a0);
      a0 = fmaf(bl(u.y), h0.z, a0); a0 = fmaf(bh(u.y), h0.w, a0);
      a0 = fmaf(bl(u.z), h1.x, a0); a0 = fmaf(bh(u.z), h1.y, a0);
      a0 = fmaf(bl(u.w), h1.z, a0); a0 = fmaf(bh(u.w), h1.w, a0);
      a1 = fmaf(bl(v.x), h0.x, a1); a1 = fmaf(bh(v.x), h0.y, a1);
      a1 = fmaf(bl(v.y), h0.z, a1); a1 = fmaf(bh(v.y), h0.w, a1);
      a1 = fmaf(bl(v.z), h1.x, a1); a1 = fmaf(bh(v.z), h1.y, a1);
      a1 = fmaf(bl(v.w), h1.z, a1); a1 = fmaf(bh(v.w), h1.w, a1);
    }
    g[j] = a0; g[j + 256] = a1;
    __syncthreads();                                   // gates ready
    if (j < 128){
      float ig = sigf(g[j]), fg = sigf(g[j + 128]);
      float gg = tanhf(g[j + 256]), og = sigf(g[j + 384]);
      c = fg * c + ig * gg;
      hn = og * tanhf(c);
      h[j] = hn;
    }
  }
  if (j < 128) comb[b * 320 + 128 + j] = hn;
}

// ---------------- scoring head (f32 weights) ----------------
__global__ void head_k(const float* __restrict__ comb, const float* __restrict__ Ws1, const float* __restrict__ bs1,
                       const float* __restrict__ Ws2, const float* __restrict__ bs2, float* __restrict__ out){
  __shared__ float cl[320];
  __shared__ float red[128];
  int b = blockIdx.x, j = threadIdx.x;   // 128 threads
  for (int k = j; k < 320; k += 128) cl[k] = comb[b * 320 + k];
  __syncthreads();
  float acc = bs1[j];
  const float4* wr = (const float4*)(Ws1 + (size_t)j * 320);
  #pragma unroll 4
  for (int kc = 0; kc < 80; ++kc){
    float4 u = wr[kc];
    int k = kc * 4;
    acc += u.x * cl[k] + u.y * cl[k + 1] + u.z * cl[k + 2] + u.w * cl[k + 3];
  }
  float hv = fmaxf(acc, 0.f);
  red[j] = hv * Ws2[j];
  __syncthreads();
  for (int s = 64; s > 0; s >>= 1){ if (j < s) red[j] += red[j + s]; __syncthreads(); }
  if (j == 0) out[b] = red[0] + bs2[0];
}

// ---------------- workspace layout (16B-aligned) ----------------
constexpr size_t OFF_OFFS   = 0;                       // (N+1) ints
constexpr size_t OFF_CNTA   = 524544;                  // NB*GB ints = 256 KB
constexpr size_t OFF_OFSA   = OFF_CNTA   + 262144;     // NB*GB ints = 256 KB
constexpr size_t OFF_BSUM   = OFF_OFSA   + 262144;     // NB ints
constexpr size_t OFF_BSUMEX = OFF_BSUM   + 1024;       // NB ints
constexpr size_t OFF_STARTS = OFF_BSUMEX + 1024;       // 257 ints
constexpr size_t OFF_SRCS   = OFF_STARTS + 2048;       // E ints = 8.4 MB
constexpr size_t OFF_WCAT1  = OFF_SRCS   + 8388608;
constexpr size_t OFF_WCAT2  = OFF_WCAT1  + 32768;
constexpr size_t OFF_WIHB   = OFF_WCAT2  + 65536;
constexpr size_t OFF_WHHB   = OFF_WIHB   + 131072;
constexpr size_t OFF_BSUMF  = OFF_WHHB   + 131072;
constexpr size_t OFF_COMB   = OFF_BSUMF  + 2048;
constexpr size_t OFF_ACAT1  = OFF_COMB   + 327680;     // N x 128 bf16; node_emb aliases after GEMM1
constexpr size_t OFF_ACAT2  = OFF_ACAT1  + 33554432;   // N x 256 bf16 (67 MB)
// aliases into the ACAT2 region (lifetimes disjoint, in execution order:
//   ebuf (sort) -> xb (agg1) -> gemm1 clobbers -> Acat2 -> pathseq/pre after gemm2):
constexpr size_t OFF_EBUF   = OFF_ACAT2;               // E unsigned (8.4 MB), dead before gemm1
constexpr size_t OFF_PATHSEQ= OFF_ACAT2;               // 8192 x 128 bf16, after gemm2
constexpr size_t OFF_PRE    = OFF_ACAT2  + 2097152;    // 8192 x 512 f32, after gemm2
constexpr size_t OFF_XB     = OFF_ACAT2  + 50331648;   // N x 64 bf16, dead before gemm1 writes Acat2

extern "C" void kernel_launch(void* const* d_in, const int* in_sizes, int n_in,
                              void* d_out, int out_size, void* d_ws, size_t ws_size,
                              hipStream_t stream){
  const float* x      = (const float*)d_in[0];
  const int* edge     = (const int*)d_in[1];
  const int* batch    = (const int*)d_in[2];
  const int* path_idx = (const int*)d_in[3];
  const int* path_len = (const int*)d_in[4];
  const float* flow   = (const float*)d_in[5];
  const float* Wl1 = (const float*)d_in[6];
  const float* Wr1 = (const float*)d_in[7];
  const float* b1  = (const float*)d_in[8];
  const float* Wl2 = (const float*)d_in[9];
  const float* Wr2 = (const float*)d_in[10];
  const float* b2  = (const float*)d_in[11];
  const float* Wih = (const float*)d_in[12];
  const float* Whh = (const float*)d_in[13];
  const float* bih = (const float*)d_in[14];
  const float* bhh = (const float*)d_in[15];
  const float* Wf  = (const float*)d_in[16];
  const float* bfv = (const float*)d_in[17];
  const float* Ws1 = (const float*)d_in[18];
  const float* bs1 = (const float*)d_in[19];
  const float* Ws2 = (const float*)d_in[20];
  const float* bs2 = (const float*)d_in[21];

  char* ws = (char*)d_ws;
  int* offs    = (int*)(ws + OFF_OFFS);
  int* cntA    = (int*)(ws + OFF_CNTA);
  int* ofsA    = (int*)(ws + OFF_OFSA);
  int* bsum    = (int*)(ws + OFF_BSUM);
  int* bsumEx  = (int*)(ws + OFF_BSUMEX);
  int* starts  = (int*)(ws + OFF_STARTS);
  int* srcS    = (int*)(ws + OFF_SRCS);
  bf16* Wcat1  = (bf16*)(ws + OFF_WCAT1);
  bf16* Wcat2  = (bf16*)(ws + OFF_WCAT2);
  bf16* WihB   = (bf16*)(ws + OFF_WIHB);
  bf16* WhhB   = (bf16*)(ws + OFF_WHHB);
  float* bsumF = (float*)(ws + OFF_BSUMF);
  float* comb  = (float*)(ws + OFF_COMB);
  bf16* Acat1  = (bf16*)(ws + OFF_ACAT1);
  bf16* node_emb = Acat1;                       // alias: Acat1 dead after GEMM1
  bf16* Acat2  = (bf16*)(ws + OFF_ACAT2);
  unsigned* ebuf = (unsigned*)(ws + OFF_EBUF);
  bf16* pathseq= (bf16*)(ws + OFF_PATHSEQ);
  float* pre   = (float*)(ws + OFF_PRE);
  bf16* xb     = (bf16*)(ws + OFF_XB);

  prep_k<<<707, 256, 0, stream>>>(Wl1, Wr1, Wl2, Wr2, Wih, Whh, bih, bhh, Wcat1, Wcat2, WihB, WhhB, bsumF);
  xb16_k<<<N_NODES / 8, 256, 0, stream>>>(x, xb, Acat1);
  bounds_k<<<1, 256, 0, stream>>>(batch, starts);
  cntA_k<<<GB, 256, 0, stream>>>(edge + N_EDGES, cntA);
  scan1_k<<<NB, 256, 0, stream>>>(cntA, ofsA, bsum);
  scan2_k<<<1, NB, 0, stream>>>(bsum, bsumEx);
  passA2_k<<<GB, 256, 0, stream>>>(edge, edge + N_EDGES, ofsA, bsumEx, ebuf);
  passB_k<<<NB, 256, 0, stream>>>(ebuf, bsumEx, offs, srcS);
  agg1_k<<<N_NODES / 4, 256, 0, stream>>>(xb, offs, srcS, Acat1);
  gemm_k<<<dim3(N_NODES / 64, 1), 256, 0, stream>>>(Acat1, 128, Wcat1, 128, b1, Acat2 + 128, 256, 0, 1);
  agg2_k<<<N_NODES / 4, 256, 0, stream>>>(offs, srcS, Acat2);
  gemm_k<<<dim3(N_NODES / 64, 1), 256, 0, stream>>>(Acat2, 256, Wcat2, 256, b2, node_emb, 128, 0, 1);
  pool_k<<<BATCHES, 512, 0, stream>>>(node_emb, starts, comb);
  flow_k<<<64, 256, 0, stream>>>(flow, Wf, bfv, comb);
  gather_k<<<BATCHES * LPATH / 4, 256, 0, stream>>>(path_idx, node_emb, pathseq);
  gemm_k<<<dim3(BATCHES * LPATH / 64, 4), 256, 0, stream>>>(pathseq, 128, WihB, 128, bsumF, pre, 512, 1, 0);
  lstm_k<<<BATCHES, 256, 0, stream>>>(WhhB, pre, path_len, comb);
  head_k<<<BATCHES, 128, 0, stream>>>(comb, Ws1, bs1, Ws2, bs2, (float*)d_out);
}

// Round 6
// 458.352 us; speedup vs baseline: 2.2854x; 1.0611x over previous
//
#include <hip/hip_runtime.h>
#include <hip/hip_bf16.h>

#define N_NODES 131072
#define N_EDGES 2097152
#define BATCHES 256
#define LPATH   32
// two-level counting sort params
#define NB   256          // coarse buckets (512 nodes each)
#define NPB  512          // nodes per bucket
#define GB   256          // cntA/passA2 blocks
#define EPB  8192         // edges per block

typedef __hip_bfloat16 bf16;
using short8  = __attribute__((ext_vector_type(8))) short;
using floatx4 = __attribute__((ext_vector_type(4))) float;

__device__ __forceinline__ float bl(unsigned u){ union {unsigned x; float f;} c; c.x = u << 16; return c.f; }
__device__ __forceinline__ float bh(unsigned u){ union {unsigned x; float f;} c; c.x = u & 0xffff0000u; return c.f; }
__device__ __forceinline__ unsigned packbf(float lo, float hi){
  bf16 l = __float2bfloat16(lo), h = __float2bfloat16(hi);
  unsigned short lu, hu;
  __builtin_memcpy(&lu, &l, 2); __builtin_memcpy(&hu, &h, 2);
  return (unsigned)lu | ((unsigned)hu << 16);
}
__device__ __forceinline__ float frcp(float x){ return __builtin_amdgcn_rcpf(x); }
__device__ __forceinline__ float sigf(float x){ return frcp(1.f + __expf(-x)); }
__device__ __forceinline__ float tanh_fast(float x){ return fmaf(2.f, frcp(1.f + __expf(-2.f * x)), -1.f); }

// ---------------- prep: f32 weights -> bf16 (concat along K for SAGE layers) ----------------
__global__ void prep_k(const float* __restrict__ Wl1, const float* __restrict__ Wr1,
                       const float* __restrict__ Wl2, const float* __restrict__ Wr2,
                       const float* __restrict__ Wih, const float* __restrict__ Whh,
                       const float* __restrict__ bih, const float* __restrict__ bhh,
                       bf16* __restrict__ Wcat1, bf16* __restrict__ Wcat2,
                       bf16* __restrict__ WihB, bf16* __restrict__ WhhB, float* __restrict__ bsumF){
  int g = blockIdx.x * 256 + threadIdx.x;
  if (g < 16384) {                    // Wcat1: 128 x 128 (Wl1 | Wr1), K split at 64
    int h = g >> 7, k = g & 127;
    float v = (k < 64) ? Wl1[h * 64 + k] : Wr1[h * 64 + (k - 64)];
    Wcat1[g] = __float2bfloat16(v);
  } else if (g < 49152) {             // Wcat2: 128 x 256 (Wl2 | Wr2), K split at 128
    int q = g - 16384;
    int h = q >> 8, k = q & 255;
    float v = (k < 128) ? Wl2[h * 128 + k] : Wr2[h * 128 + (k - 128)];
    Wcat2[q] = __float2bfloat16(v);
  } else if (g < 114688) {            // WihB: 512 x 128
    int q = g - 49152;
    WihB[q] = __float2bfloat16(Wih[q]);
  } else if (g < 180224) {            // WhhB: 512 x 128
    int q = g - 114688;
    WhhB[q] = __float2bfloat16(Whh[q]);
  } else if (g < 180736) {            // bsumF = bih + bhh (f32)
    int k = g - 180224;
    bsumF[k] = bih[k] + bhh[k];
  }
}

// ---------------- x (f32) -> xb (bf16) + self-half of Acat1 ----------------
__global__ void xb16_k(const float* __restrict__ x, bf16* __restrict__ xb, bf16* __restrict__ Acat1){
  int g = blockIdx.x * 256 + threadIdx.x;     // one thread per 2 features
  int n = g >> 5, p = g & 31;
  float2 v = *(const float2*)(x + (size_t)n * 64 + p * 2);
  unsigned u = packbf(v.x, v.y);
  *(unsigned*)(xb + (size_t)n * 64 + p * 2) = u;
  *(unsigned*)(Acat1 + (size_t)n * 128 + 64 + p * 2) = u;
}

// ---------------- graph segment bounds (batch is sorted) ----------------
__global__ void bounds_k(const int* __restrict__ batch, int* __restrict__ starts){
  int b = threadIdx.x;
  int lo = 0, hi = N_NODES;
  while (lo < hi){ int mid = (lo + hi) >> 1; if (batch[mid] < b) lo = mid + 1; else hi = mid; }
  starts[b] = lo;
  if (b == 0) starts[BATCHES] = N_NODES;
}

// ---------------- CSR build: two-level counting sort (no global atomics) ----------------
__global__ void cntA_k(const int* __restrict__ dst, int* __restrict__ cntA){
  __shared__ int h[NB];
  int tid = threadIdx.x;
  h[tid] = 0;
  __syncthreads();
  int base = blockIdx.x * EPB;
  #pragma unroll
  for (int i = 0; i < EPB / 256; ++i){
    int d = dst[base + i * 256 + tid];
    atomicAdd(&h[d >> 9], 1);
  }
  __syncthreads();
  cntA[tid * GB + blockIdx.x] = h[tid];
}

__global__ void scan1_k(const int* __restrict__ cnt, int* __restrict__ ofsA, int* __restrict__ bsum){
  __shared__ int sh[256];
  int t = threadIdx.x, i = blockIdx.x * 256 + t;
  int v = cnt[i];
  sh[t] = v; __syncthreads();
  int inc = v;
  for (int d = 1; d < 256; d <<= 1){
    int add = (t >= d) ? sh[t - d] : 0;
    __syncthreads();
    inc += add; sh[t] = inc;
    __syncthreads();
  }
  ofsA[i] = inc - v;
  if (t == 255) bsum[blockIdx.x] = inc;
}

__global__ void scan2_k(const int* __restrict__ bsum, int* __restrict__ bsumEx){
  __shared__ int sh[NB];
  int t = threadIdx.x;
  int v = bsum[t];
  sh[t] = v; __syncthreads();
  int inc = v;
  for (int d = 1; d < NB; d <<= 1){
    int add = (t >= d) ? sh[t - d] : 0;
    __syncthreads();
    inc += add; sh[t] = inc;
    __syncthreads();
  }
  bsumEx[t] = inc - v;
}

__global__ void passA2_k(const int* __restrict__ src, const int* __restrict__ dst,
                         const int* __restrict__ ofsA, const int* __restrict__ bsumEx,
                         unsigned* __restrict__ ebuf){
  __shared__ int cur[NB];
  int tid = threadIdx.x;
  cur[tid] = ofsA[tid * GB + blockIdx.x] + bsumEx[tid];
  __syncthreads();
  int base = blockIdx.x * EPB;
  #pragma unroll
  for (int i = 0; i < EPB / 256; ++i){
    int e = base + i * 256 + tid;
    int s = src[e], d = dst[e];
    int p = atomicAdd(&cur[d >> 9], 1);
    ebuf[p] = (unsigned)s | ((unsigned)(d & (NPB - 1)) << 17);
  }
}

__global__ void passB_k(const unsigned* __restrict__ ebuf, const int* __restrict__ bsumEx,
                        int* __restrict__ offs, int* __restrict__ srcS){
  __shared__ int ncnt[NPB];
  __shared__ int pairs[256];
  __shared__ int nofs[NPB];
  int k = blockIdx.x, tid = threadIdx.x;
  int bs = bsumEx[k];
  int be = (k < NB - 1) ? bsumEx[k + 1] : N_EDGES;
  ncnt[tid] = 0; ncnt[tid + 256] = 0;
  __syncthreads();
  for (int i = bs + tid; i < be; i += 256)
    atomicAdd(&ncnt[ebuf[i] >> 17], 1);
  __syncthreads();
  int p = ncnt[2 * tid] + ncnt[2 * tid + 1];
  pairs[tid] = p;
  __syncthreads();
  int inc = p;
  for (int d = 1; d < 256; d <<= 1){
    int add = (tid >= d) ? pairs[tid - d] : 0;
    __syncthreads();
    inc += add; pairs[tid] = inc;
    __syncthreads();
  }
  int ex = inc - p;
  nofs[2 * tid]     = ex;
  nofs[2 * tid + 1] = ex + ncnt[2 * tid];
  __syncthreads();
  offs[k * NPB + tid]       = bs + nofs[tid];
  offs[k * NPB + tid + 256] = bs + nofs[tid + 256];
  if (k == NB - 1 && tid == 0) offs[N_NODES] = N_EDGES;
  ncnt[tid] = nofs[tid]; ncnt[tid + 256] = nofs[tid + 256];
  __syncthreads();
  for (int i = bs + tid; i < be; i += 256){
    unsigned w = ebuf[i];
    int loc = w >> 17, sv = w & 0x1FFFF;
    int pp = atomicAdd(&ncnt[loc], 1);
    srcS[bs + pp] = sv;
  }
}

// ---------------- SAGE layer-1 aggregation: mean of xb[src], 8 edge-slots x 8 lanes x uint4 ----------------
__global__ void agg1_k(const bf16* __restrict__ xb, const int* __restrict__ offs,
                       const int* __restrict__ srcS, bf16* __restrict__ Acat1){
  int wid = threadIdx.x >> 6, lane = threadIdx.x & 63;
  int n = blockIdx.x * 4 + wid;
  int s = offs[n], e = offs[n + 1];
  int slot = lane >> 3, fl = lane & 7;
  float a0=0,a1=0,a2=0,a3=0,a4=0,a5=0,a6=0,a7=0;
  float c0=0,c1=0,c2=0,c3=0,c4=0,c5=0,c6=0,c7=0;
  int i = s + slot;
  for (; i + 8 < e; i += 16){
    int sv0 = srcS[i], sv1 = srcS[i + 8];
    uint4 u = *(const uint4*)(xb + (size_t)sv0 * 64 + fl * 8);
    uint4 v = *(const uint4*)(xb + (size_t)sv1 * 64 + fl * 8);
    a0 += bl(u.x); a1 += bh(u.x); a2 += bl(u.y); a3 += bh(u.y);
    a4 += bl(u.z); a5 += bh(u.z); a6 += bl(u.w); a7 += bh(u.w);
    c0 += bl(v.x); c1 += bh(v.x); c2 += bl(v.y); c3 += bh(v.y);
    c4 += bl(v.z); c5 += bh(v.z); c6 += bl(v.w); c7 += bh(v.w);
  }
  if (i < e){
    int sv0 = srcS[i];
    uint4 u = *(const uint4*)(xb + (size_t)sv0 * 64 + fl * 8);
    a0 += bl(u.x); a1 += bh(u.x); a2 += bl(u.y); a3 += bh(u.y);
    a4 += bl(u.z); a5 += bh(u.z); a6 += bl(u.w); a7 += bh(u.w);
  }
  a0 += c0; a1 += c1; a2 += c2; a3 += c3;
  a4 += c4; a5 += c5; a6 += c6; a7 += c7;
  a0 += __shfl_xor(a0, 8); a0 += __shfl_xor(a0, 16); a0 += __shfl_xor(a0, 32);
  a1 += __shfl_xor(a1, 8); a1 += __shfl_xor(a1, 16); a1 += __shfl_xor(a1, 32);
  a2 += __shfl_xor(a2, 8); a2 += __shfl_xor(a2, 16); a2 += __shfl_xor(a2, 32);
  a3 += __shfl_xor(a3, 8); a3 += __shfl_xor(a3, 16); a3 += __shfl_xor(a3, 32);
  a4 += __shfl_xor(a4, 8); a4 += __shfl_xor(a4, 16); a4 += __shfl_xor(a4, 32);
  a5 += __shfl_xor(a5, 8); a5 += __shfl_xor(a5, 16); a5 += __shfl_xor(a5, 32);
  a6 += __shfl_xor(a6, 8); a6 += __shfl_xor(a6, 16); a6 += __shfl_xor(a6, 32);
  a7 += __shfl_xor(a7, 8); a7 += __shfl_xor(a7, 16); a7 += __shfl_xor(a7, 32);
  if (slot == 0){
    int d = e - s; if (d < 1) d = 1;
    float inv = 1.f / (float)d;
    uint4 w;
    w.x = packbf(a0 * inv, a1 * inv); w.y = packbf(a2 * inv, a3 * inv);
    w.z = packbf(a4 * inv, a5 * inv); w.w = packbf(a6 * inv, a7 * inv);
    *(uint4*)(Acat1 + (size_t)n * 128 + fl * 8) = w;
  }
}

// ---------------- SAGE layer-2 aggregation: mean of h1[src], 4 edge-slots x 16 lanes x uint4 ----------------
__global__ void agg2_k(const int* __restrict__ offs, const int* __restrict__ srcS, bf16* __restrict__ Acat2){
  int wid = threadIdx.x >> 6, lane = threadIdx.x & 63;
  int n = blockIdx.x * 4 + wid;
  int s = offs[n], e = offs[n + 1];
  int slot = lane >> 4, fl = lane & 15;
  float a0=0,a1=0,a2=0,a3=0,a4=0,a5=0,a6=0,a7=0;
  float c0=0,c1=0,c2=0,c3=0,c4=0,c5=0,c6=0,c7=0;
  int i = s + slot;
  for (; i + 4 < e; i += 8){
    int sv0 = srcS[i], sv1 = srcS[i + 4];
    uint4 u = *(const uint4*)(Acat2 + (size_t)sv0 * 256 + 128 + fl * 8);
    uint4 v = *(const uint4*)(Acat2 + (size_t)sv1 * 256 + 128 + fl * 8);
    a0 += bl(u.x); a1 += bh(u.x); a2 += bl(u.y); a3 += bh(u.y);
    a4 += bl(u.z); a5 += bh(u.z); a6 += bl(u.w); a7 += bh(u.w);
    c0 += bl(v.x); c1 += bh(v.x); c2 += bl(v.y); c3 += bh(v.y);
    c4 += bl(v.z); c5 += bh(v.z); c6 += bl(v.w); c7 += bh(v.w);
  }
  if (i < e){
    int sv0 = srcS[i];
    uint4 u = *(const uint4*)(Acat2 + (size_t)sv0 * 256 + 128 + fl * 8);
    a0 += bl(u.x); a1 += bh(u.x); a2 += bl(u.y); a3 += bh(u.y);
    a4 += bl(u.z); a5 += bh(u.z); a6 += bl(u.w); a7 += bh(u.w);
  }
  a0 += c0; a1 += c1; a2 += c2; a3 += c3;
  a4 += c4; a5 += c5; a6 += c6; a7 += c7;
  a0 += __shfl_xor(a0, 16); a0 += __shfl_xor(a0, 32);
  a1 += __shfl_xor(a1, 16); a1 += __shfl_xor(a1, 32);
  a2 += __shfl_xor(a2, 16); a2 += __shfl_xor(a2, 32);
  a3 += __shfl_xor(a3, 16); a3 += __shfl_xor(a3, 32);
  a4 += __shfl_xor(a4, 16); a4 += __shfl_xor(a4, 32);
  a5 += __shfl_xor(a5, 16); a5 += __shfl_xor(a5, 32);
  a6 += __shfl_xor(a6, 16); a6 += __shfl_xor(a6, 32);
  a7 += __shfl_xor(a7, 16); a7 += __shfl_xor(a7, 32);
  if (slot == 0){
    int d = e - s; if (d < 1) d = 1;
    float inv = 1.f / (float)d;
    uint4 w;
    w.x = packbf(a0 * inv, a1 * inv); w.y = packbf(a2 * inv, a3 * inv);
    w.z = packbf(a4 * inv, a5 * inv); w.w = packbf(a6 * inv, a7 * inv);
    *(uint4*)(Acat2 + (size_t)n * 256 + fl * 8) = w;
  }
}

// ---------------- generic MFMA GEMM: out[M x Ncols] = act(A[M x K] @ W[Ncols x K]^T + bias) ----------------
__global__ __launch_bounds__(256) void gemm_k(const bf16* __restrict__ A, int lda,
                                              const bf16* __restrict__ W, int K,
                                              const float* __restrict__ bias,
                                              void* __restrict__ out, int ldo, int outF32, int relu){
  __shared__ bf16 Wl[128][136];   // +8 pad: 2-way bank aliasing only
  int tid = threadIdx.x;
  int wid = tid >> 6, lane = tid & 63;
  int l16 = lane & 15, quad = lane >> 4;
  int rowBase  = blockIdx.x * 64 + wid * 16;
  int colGroup = blockIdx.y * 128;
  floatx4 acc[8] = {};
  int nStage = K >> 7;
  for (int ks = 0; ks < nStage; ++ks){
    __syncthreads();
    for (int c = tid; c < 2048; c += 256){
      int r = c >> 4, kc = (c & 15) << 3;
      *(uint4*)(&Wl[r][kc]) = *(const uint4*)(W + (size_t)(colGroup + r) * K + ks * 128 + kc);
    }
    __syncthreads();
    for (int kk = 0; kk < 4; ++kk){
      short8 af = *(const short8*)(A + (size_t)(rowBase + l16) * lda + ks * 128 + kk * 32 + quad * 8);
      #pragma unroll
      for (int c = 0; c < 8; ++c){
        short8 bq = *(const short8*)(&Wl[c * 16 + l16][kk * 32 + quad * 8]);
        acc[c] = __builtin_amdgcn_mfma_f32_16x16x32_bf16(af, bq, acc[c], 0, 0, 0);
      }
    }
  }
  #pragma unroll
  for (int c = 0; c < 8; ++c){
    int col = colGroup + c * 16 + l16;
    float bv = bias ? bias[col] : 0.f;
    #pragma unroll
    for (int r = 0; r < 4; ++r){
      int row = rowBase + quad * 4 + r;
      float v = acc[c][r] + bv;
      if (relu) v = fmaxf(v, 0.f);
      if (outF32) ((float*)out)[(size_t)row * ldo + col] = v;
      else        ((bf16*)out)[(size_t)row * ldo + col]  = __float2bfloat16(v);
    }
  }
}

// ---------------- graph mean pooling: 512 thr, 8-way row split + LDS reduce ----------------
__global__ void pool_k(const bf16* __restrict__ ne, const int* __restrict__ starts, float* __restrict__ comb){
  __shared__ float sh[8][128];
  int b = blockIdx.x;
  int q = threadIdx.x >> 6, lane = threadIdx.x & 63;   // 512 threads: 8 slots x 64 lanes
  int s = starts[b], e = starts[b + 1];
  float a0 = 0.f, a1 = 0.f;
  for (int i = s + q; i < e; i += 8){
    unsigned u = *(const unsigned*)(ne + (size_t)i * 128 + lane * 2);
    a0 += bl(u); a1 += bh(u);
  }
  sh[q][lane * 2] = a0; sh[q][lane * 2 + 1] = a1;
  __syncthreads();
  if (threadIdx.x < 128){
    int f = threadIdx.x;
    float tot = 0.f;
    #pragma unroll
    for (int k = 0; k < 8; ++k) tot += sh[k][f];
    int d = e - s; if (d < 1) d = 1;
    comb[b * 320 + f] = tot / (float)d;
  }
}

// ---------------- flow MLP: relu(flow @ Wf^T + bf), all f32 ----------------
__global__ void flow_k(const float* __restrict__ flow, const float* __restrict__ Wf,
                       const float* __restrict__ bfv, float* __restrict__ comb){
  int g = blockIdx.x * 256 + threadIdx.x;
  int b = g >> 6, j = g & 63;
  float acc = bfv[j];
  for (int k = 0; k < 16; ++k)
    acc += flow[b * 16 + k] * Wf[j * 16 + k];
  comb[b * 320 + 256 + j] = fmaxf(acc, 0.f);
}

// ---------------- gather path sequences (bf16 node_emb rows) ----------------
__global__ void gather_k(const int* __restrict__ path_idx, const bf16* __restrict__ ne, bf16* __restrict__ ps){
  int wid = threadIdx.x >> 6, lane = threadIdx.x & 63;
  int r = blockIdx.x * 4 + wid;          // r in [0, B*L)
  int idx = path_idx[r];
  ((unsigned*)ps)[(size_t)r * 64 + lane] = ((const unsigned*)ne)[(size_t)idx * 64 + lane];
}

// ---------------- LSTM recurrence via MFMA: 16 batches/block, 16 blocks ----------------
// wave w owns h-dims [32w, 32w+32) of all four gates (i,f,g,o) -> c/h update is lane-local.
// gates[16 x 512] = h[16 x 128](bf16, LDS dbuf) @ Whh^T via 32x mfma_16x16x32 per wave per step.
// pre (x@Wih^T + biases, f32) prefetched one step ahead, folded into accumulator init.
__global__ __launch_bounds__(256, 1) void lstm_k(const bf16* __restrict__ Whh, const float* __restrict__ pre,
                                                 const int* __restrict__ path_len, float* __restrict__ comb){
  __shared__ bf16 hbuf[2][16][136];   // [buf][batch][dim], +8 pad
  int tid = threadIdx.x;
  int w = tid >> 6, lane = tid & 63;
  int l16 = lane & 15, quad = lane >> 4;
  int b0 = blockIdx.x * 16;

  // Whh B-fragments: wb[q][hf][ks] = Whh[n = q*128 + w*32 + hf*16 + l16][ks*32 + quad*8 .. +8]
  short8 wb[4][2][4];
  #pragma unroll
  for (int q = 0; q < 4; ++q)
    #pragma unroll
    for (int hf = 0; hf < 2; ++hf){
      const bf16* rp = Whh + (size_t)(q * 128 + w * 32 + hf * 16 + l16) * 128 + quad * 8;
      #pragma unroll
      for (int ks = 0; ks < 4; ++ks) wb[q][hf][ks] = *(const short8*)(rp + ks * 32);
    }

  // per-lane batch lengths (rows quad*4+r) and block max length
  int lenr[4];
  #pragma unroll
  for (int r = 0; r < 4; ++r){
    int L = path_len[b0 + quad * 4 + r];
    if (L < 1) L = 1; if (L > LPATH) L = LPATH;
    lenr[r] = L;
  }
  int maxlen = 1;
  for (int i = 0; i < 16; ++i){
    int L = path_len[b0 + i];
    if (L > LPATH) L = LPATH;
    if (L > maxlen) maxlen = L;
  }

  // zero h buffer 0
  for (int i = tid; i < 1088; i += 256) ((unsigned*)&hbuf[0][0][0])[i] = 0;

  // pre base pointers per (row r): pre[(b0+row)*LPATH*512 + t*512 + col]
  const float* pb[4];
  #pragma unroll
  for (int r = 0; r < 4; ++r)
    pb[r] = pre + (size_t)(b0 + quad * 4 + r) * LPATH * 512 + w * 32 + l16;

  // prologue: load pre for t=0
  float pv[4][2][4];
  #pragma unroll
  for (int q = 0; q < 4; ++q)
    #pragma unroll
    for (int hf = 0; hf < 2; ++hf)
      #pragma unroll
      for (int r = 0; r < 4; ++r)
        pv[q][hf][r] = pb[r][q * 128 + hf * 16];

  float cst[2][4] = {}, hst[2][4] = {};

  for (int t = 0; t < maxlen; ++t){
    int cur = t & 1, nxt = cur ^ 1;
    __syncthreads();                           // hbuf[cur] ready
    // A-fragments of h
    short8 af[4];
    #pragma unroll
    for (int ks = 0; ks < 4; ++ks)
      af[ks] = *(const short8*)(&hbuf[cur][l16][ks * 32 + quad * 8]);
    // prefetch pre for t+1 (clamped; fully hidden behind mfma+epilogue)
    int tn = (t + 1 < maxlen) ? t + 1 : t;
    float pnext[4][2][4];
    #pragma unroll
    for (int q = 0; q < 4; ++q)
      #pragma unroll
      for (int hf = 0; hf < 2; ++hf)
        #pragma unroll
        for (int r = 0; r < 4; ++r)
          pnext[q][hf][r] = pb[r][tn * 512 + q * 128 + hf * 16];
    // acc init = pre(t) (C-layout match: reg r <-> row quad*4+r)
    floatx4 acc[4][2];
    #pragma unroll
    for (int q = 0; q < 4; ++q)
      #pragma unroll
      for (int hf = 0; hf < 2; ++hf){
        acc[q][hf][0] = pv[q][hf][0]; acc[q][hf][1] = pv[q][hf][1];
        acc[q][hf][2] = pv[q][hf][2]; acc[q][hf][3] = pv[q][hf][3];
      }
    #pragma unroll
    for (int ks = 0; ks < 4; ++ks)
      #pragma unroll
      for (int q = 0; q < 4; ++q)
        #pragma unroll
        for (int hf = 0; hf < 2; ++hf)
          acc[q][hf] = __builtin_amdgcn_mfma_f32_16x16x32_bf16(af[ks], wb[q][hf][ks], acc[q][hf], 0, 0, 0);
    // gate nonlinearity + state update (lane-local) + h write to hbuf[nxt]
    #pragma unroll
    for (int hf = 0; hf < 2; ++hf)
      #pragma unroll
      for (int r = 0; r < 4; ++r){
        float ig = sigf(acc[0][hf][r]);
        float fg = sigf(acc[1][hf][r]);
        float gg = tanh_fast(acc[2][hf][r]);
        float og = sigf(acc[3][hf][r]);
        float cn = fmaf(fg, cst[hf][r], ig * gg);
        float hn = og * tanh_fast(cn);
        bool vld = t < lenr[r];
        cst[hf][r] = vld ? cn : cst[hf][r];
        hst[hf][r] = vld ? hn : hst[hf][r];
        hbuf[nxt][quad * 4 + r][w * 32 + hf * 16 + l16] = __float2bfloat16(hst[hf][r]);
      }
    // roll prefetch
    #pragma unroll
    for (int q = 0; q < 4; ++q)
      #pragma unroll
      for (int hf = 0; hf < 2; ++hf)
        #pragma unroll
        for (int r = 0; r < 4; ++r)
          pv[q][hf][r] = pnext[q][hf][r];
  }

  #pragma unroll
  for (int hf = 0; hf < 2; ++hf)
    #pragma unroll
    for (int r = 0; r < 4; ++r)
      comb[(b0 + quad * 4 + r) * 320 + 128 + w * 32 + hf * 16 + l16] = hst[hf][r];
}

// ---------------- scoring head (f32 weights) ----------------
__global__ void head_k(const float* __restrict__ comb, const float* __restrict__ Ws1, const float* __restrict__ bs1,
                       const float* __restrict__ Ws2, const float* __restrict__ bs2, float* __restrict__ out){
  __shared__ float cl[320];
  __shared__ float red[128];
  int b = blockIdx.x, j = threadIdx.x;   // 128 threads
  for (int k = j; k < 320; k += 128) cl[k] = comb[b * 320 + k];
  __syncthreads();
  float acc = bs1[j];
  const float4* wr = (const float4*)(Ws1 + (size_t)j * 320);
  #pragma unroll 4
  for (int kc = 0; kc < 80; ++kc){
    float4 u = wr[kc];
    int k = kc * 4;
    acc += u.x * cl[k] + u.y * cl[k + 1] + u.z * cl[k + 2] + u.w * cl[k + 3];
  }
  float hv = fmaxf(acc, 0.f);
  red[j] = hv * Ws2[j];
  __syncthreads();
  for (int s = 64; s > 0; s >>= 1){ if (j < s) red[j] += red[j + s]; __syncthreads(); }
  if (j == 0) out[b] = red[0] + bs2[0];
}

// ---------------- workspace layout (16B-aligned) ----------------
constexpr size_t OFF_OFFS   = 0;                       // (N+1) ints
constexpr size_t OFF_CNTA   = 524544;                  // NB*GB ints = 256 KB
constexpr size_t OFF_OFSA   = OFF_CNTA   + 262144;     // NB*GB ints = 256 KB
constexpr size_t OFF_BSUM   = OFF_OFSA   + 262144;     // NB ints
constexpr size_t OFF_BSUMEX = OFF_BSUM   + 1024;       // NB ints
constexpr size_t OFF_STARTS = OFF_BSUMEX + 1024;       // 257 ints
constexpr size_t OFF_SRCS   = OFF_STARTS + 2048;       // E ints = 8.4 MB
constexpr size_t OFF_WCAT1  = OFF_SRCS   + 8388608;
constexpr size_t OFF_WCAT2  = OFF_WCAT1  + 32768;
constexpr size_t OFF_WIHB   = OFF_WCAT2  + 65536;
constexpr size_t OFF_WHHB   = OFF_WIHB   + 131072;
constexpr size_t OFF_BSUMF  = OFF_WHHB   + 131072;
constexpr size_t OFF_COMB   = OFF_BSUMF  + 2048;
constexpr size_t OFF_ACAT1  = OFF_COMB   + 327680;     // N x 128 bf16; node_emb aliases after GEMM1
constexpr size_t OFF_ACAT2  = OFF_ACAT1  + 33554432;   // N x 256 bf16 (67 MB)
// aliases into the ACAT2 region (lifetimes disjoint):
constexpr size_t OFF_EBUF   = OFF_ACAT2;               // E unsigned (8.4 MB), dead before gemm1
constexpr size_t OFF_PATHSEQ= OFF_ACAT2;               // 8192 x 128 bf16, after gemm2
constexpr size_t OFF_PRE    = OFF_ACAT2  + 2097152;    // 8192 x 512 f32, after gemm2
constexpr size_t OFF_XB     = OFF_ACAT2  + 50331648;   // N x 64 bf16, dead before gemm1 writes Acat2

extern "C" void kernel_launch(void* const* d_in, const int* in_sizes, int n_in,
                              void* d_out, int out_size, void* d_ws, size_t ws_size,
                              hipStream_t stream){
  const float* x      = (const float*)d_in[0];
  const int* edge     = (const int*)d_in[1];
  const int* batch    = (const int*)d_in[2];
  const int* path_idx = (const int*)d_in[3];
  const int* path_len = (const int*)d_in[4];
  const float* flow   = (const float*)d_in[5];
  const float* Wl1 = (const float*)d_in[6];
  const float* Wr1 = (const float*)d_in[7];
  const float* b1  = (const float*)d_in[8];
  const float* Wl2 = (const float*)d_in[9];
  const float* Wr2 = (const float*)d_in[10];
  const float* b2  = (const float*)d_in[11];
  const float* Wih = (const float*)d_in[12];
  const float* Whh = (const float*)d_in[13];
  const float* bih = (const float*)d_in[14];
  const float* bhh = (const float*)d_in[15];
  const float* Wf  = (const float*)d_in[16];
  const float* bfv = (const float*)d_in[17];
  const float* Ws1 = (const float*)d_in[18];
  const float* bs1 = (const float*)d_in[19];
  const float* Ws2 = (const float*)d_in[20];
  const float* bs2 = (const float*)d_in[21];

  char* ws = (char*)d_ws;
  int* offs    = (int*)(ws + OFF_OFFS);
  int* cntA    = (int*)(ws + OFF_CNTA);
  int* ofsA    = (int*)(ws + OFF_OFSA);
  int* bsum    = (int*)(ws + OFF_BSUM);
  int* bsumEx  = (int*)(ws + OFF_BSUMEX);
  int* starts  = (int*)(ws + OFF_STARTS);
  int* srcS    = (int*)(ws + OFF_SRCS);
  bf16* Wcat1  = (bf16*)(ws + OFF_WCAT1);
  bf16* Wcat2  = (bf16*)(ws + OFF_WCAT2);
  bf16* WihB   = (bf16*)(ws + OFF_WIHB);
  bf16* WhhB   = (bf16*)(ws + OFF_WHHB);
  float* bsumF = (float*)(ws + OFF_BSUMF);
  float* comb  = (float*)(ws + OFF_COMB);
  bf16* Acat1  = (bf16*)(ws + OFF_ACAT1);
  bf16* node_emb = Acat1;                       // alias: Acat1 dead after GEMM1
  bf16* Acat2  = (bf16*)(ws + OFF_ACAT2);
  unsigned* ebuf = (unsigned*)(ws + OFF_EBUF);
  bf16* pathseq= (bf16*)(ws + OFF_PATHSEQ);
  float* pre   = (float*)(ws + OFF_PRE);
  bf16* xb     = (bf16*)(ws + OFF_XB);

  prep_k<<<707, 256, 0, stream>>>(Wl1, Wr1, Wl2, Wr2, Wih, Whh, bih, bhh, Wcat1, Wcat2, WihB, WhhB, bsumF);
  xb16_k<<<N_NODES / 8, 256, 0, stream>>>(x, xb, Acat1);
  bounds_k<<<1, 256, 0, stream>>>(batch, starts);
  cntA_k<<<GB, 256, 0, stream>>>(edge + N_EDGES, cntA);
  scan1_k<<<NB, 256, 0, stream>>>(cntA, ofsA, bsum);
  scan2_k<<<1, NB, 0, stream>>>(bsum, bsumEx);
  passA2_k<<<GB, 256, 0, stream>>>(edge, edge + N_EDGES, ofsA, bsumEx, ebuf);
  passB_k<<<NB, 256, 0, stream>>>(ebuf, bsumEx, offs, srcS);
  agg1_k<<<N_NODES / 4, 256, 0, stream>>>(xb, offs, srcS, Acat1);
  gemm_k<<<dim3(N_NODES / 64, 1), 256, 0, stream>>>(Acat1, 128, Wcat1, 128, b1, Acat2 + 128, 256, 0, 1);
  agg2_k<<<N_NODES / 4, 256, 0, stream>>>(offs, srcS, Acat2);
  gemm_k<<<dim3(N_NODES / 64, 1), 256, 0, stream>>>(Acat2, 256, Wcat2, 256, b2, node_emb, 128, 0, 1);
  pool_k<<<BATCHES, 512, 0, stream>>>(node_emb, starts, comb);
  flow_k<<<64, 256, 0, stream>>>(flow, Wf, bfv, comb);
  gather_k<<<BATCHES * LPATH / 4, 256, 0, stream>>>(path_idx, node_emb, pathseq);
  gemm_k<<<dim3(BATCHES * LPATH / 64, 4), 256, 0, stream>>>(pathseq, 128, WihB, 128, bsumF, pre, 512, 1, 0);
  lstm_k<<<BATCHES / 16, 256, 0, stream>>>(WhhB, pre, path_len, comb);
  head_k<<<BATCHES, 128, 0, stream>>>(comb, Ws1, bs1, Ws2, bs2, (float*)d_out);
}